// Round 11
// baseline (1528.440 us; speedup 1.0000x reference)
//
#include <hip/hip_runtime.h>
#include <cstdint>

#define NNODES 100000
#define NEDGES 600000
#define NETYPES 4
#define DIM 128
#define NSTEPS 8
#define NGRAPHS 128
#define NBINS (NETYPES * NNODES)
#define SCAN_BLK 391  // ceil(NBINS/1024)
#define NTILES (NNODES / 32)
#define PGRID 512
#define GRU_GRID 512

typedef short s16x8 __attribute__((ext_vector_type(8)));
typedef float f32x4 __attribute__((ext_vector_type(4)));

#define MFMA(a, b, c) __builtin_amdgcn_mfma_f32_16x16x32_bf16(a, b, c, 0, 0, 0)

static __device__ inline unsigned short f2bf(float x) {
  unsigned int u = __float_as_uint(x);
  unsigned int r = (u + 0x7FFFu + ((u >> 16) & 1u)) >> 16;
  return (unsigned short)r;
}
static __device__ inline float bf2f(unsigned short b) {
  return __uint_as_float(((unsigned int)b) << 16);
}

// ---------------- diagnostic fill ----------------
__global__ __launch_bounds__(128) void fill_kernel(float* __restrict__ out, int n, float v) {
  int i = blockIdx.x * 128 + threadIdx.x;
  if (i < n) out[i] = v;
}

// ---------------- fp32 -> bf16 converts ----------------
__global__ __launch_bounds__(256) void cvt_h_kernel(const float* __restrict__ f,
                                                    unsigned short* __restrict__ h, int n4) {
  int i = blockIdx.x * 256 + threadIdx.x;
  if (i < n4) {
    float4 v = ((const float4*)f)[i];
    ushort4 u = {f2bf(v.x), f2bf(v.y), f2bf(v.z), f2bf(v.w)};
    ((ushort4*)h)[i] = u;
  }
}

// W_edge [e][d][h] fp32 -> WeT [e][h][d] bf16 (j-major, k-contiguous)
__global__ __launch_bounds__(256) void cvt_we_kernel(const float* __restrict__ W,
                                                     unsigned short* __restrict__ WT) {
  int i = blockIdx.x * 256 + threadIdx.x;
  if (i < NETYPES * DIM * DIM) {
    int e = i >> 14;
    int r = i & 16383;
    int d = r >> 7;   // k
    int j = r & 127;  // output col
    WT[(e << 14) + (j << 7) + d] = f2bf(W[i]);
  }
}

__global__ __launch_bounds__(256) void cvt_w_kernel(const float* __restrict__ W,
                                                    unsigned short* __restrict__ Wb, int n) {
  int i = blockIdx.x * 256 + threadIdx.x;
  if (i < n) Wb[i] = f2bf(W[i]);
}

// ---------------- CSR build: histogram / scan / fill ----------------
__global__ __launch_bounds__(256) void hist_kernel(const int* __restrict__ edst,
                                                   const int* __restrict__ etyp,
                                                   int* __restrict__ bins) {
  int e = blockIdx.x * 256 + threadIdx.x;
  if (e < NEDGES) atomicAdd(&bins[etyp[e] * NNODES + edst[e]], 1);
}

__global__ __launch_bounds__(256) void scan1_kernel(const int* __restrict__ bins,
                                                    int* __restrict__ rp,
                                                    int* __restrict__ bsum) {
  __shared__ int sh[256];
  int b = blockIdx.x, t = threadIdx.x;
  int base = b * 1024 + t * 4;
  int v0 = 0, v1 = 0, v2 = 0, v3 = 0;
  if (base + 3 < NBINS) {
    int4 q = *(const int4*)(bins + base);
    v0 = q.x; v1 = q.y; v2 = q.z; v3 = q.w;
  } else {
    if (base < NBINS) v0 = bins[base];
    if (base + 1 < NBINS) v1 = bins[base + 1];
    if (base + 2 < NBINS) v2 = bins[base + 2];
  }
  int s = v0 + v1 + v2 + v3;
  sh[t] = s;
  __syncthreads();
  for (int off = 1; off < 256; off <<= 1) {
    int x = (t >= off) ? sh[t - off] : 0;
    __syncthreads();
    if (t >= off) sh[t] += x;
    __syncthreads();
  }
  int run = sh[t] - s;
  if (t == 255) bsum[b] = sh[255];
  if (base < NBINS) rp[base] = run;
  run += v0;
  if (base + 1 < NBINS) rp[base + 1] = run;
  run += v1;
  if (base + 2 < NBINS) rp[base + 2] = run;
  run += v2;
  if (base + 3 < NBINS) rp[base + 3] = run;
}

__global__ __launch_bounds__(512) void scan2_kernel(const int* __restrict__ bsum,
                                                    int* __restrict__ boffs,
                                                    int* __restrict__ rp) {
  __shared__ int sh[512];
  int t = threadIdx.x;
  int v = (t < SCAN_BLK) ? bsum[t] : 0;
  sh[t] = v;
  __syncthreads();
  for (int off = 1; off < 512; off <<= 1) {
    int x = (t >= off) ? sh[t - off] : 0;
    __syncthreads();
    if (t >= off) sh[t] += x;
    __syncthreads();
  }
  if (t < SCAN_BLK) boffs[t] = sh[t] - v;
  if (t == SCAN_BLK - 1) rp[NBINS] = sh[t];
}

__global__ __launch_bounds__(256) void scan3_kernel(int* __restrict__ rp,
                                                    const int* __restrict__ boffs) {
  int b = blockIdx.x, t = threadIdx.x;
  int base = b * 1024 + t * 4;
  int off = boffs[b];
#pragma unroll
  for (int i = 0; i < 4; ++i)
    if (base + i < NBINS) rp[base + i] += off;
}

__global__ __launch_bounds__(256) void fill_edges_kernel(const int* __restrict__ esrc,
                                                         const int* __restrict__ edst,
                                                         const int* __restrict__ etyp,
                                                         int* __restrict__ cursor,
                                                         int* __restrict__ esrc_s) {
  int e = blockIdx.x * 256 + threadIdx.x;
  if (e < NEDGES) {
    int slot = atomicAdd(&cursor[etyp[e] * NNODES + edst[e]], 1);
    esrc_s[slot] = esrc[e];
  }
}

// ---------------- K1 (split path): 4-way interleaved gather ----------------
__global__ __launch_bounds__(256) void agg4_ilv_kernel(const unsigned short* __restrict__ hbf,
                                                       const int* __restrict__ rp,
                                                       const int* __restrict__ esrc_s,
                                                       unsigned short* __restrict__ agg4) {
  int w = (blockIdx.x * 256 + threadIdx.x) >> 6;
  int lane = threadIdx.x & 63;
  if (w >= NNODES) return;
  int beg[4], len[4];
#pragma unroll
  for (int ty = 0; ty < 4; ++ty) {
    beg[ty] = rp[ty * NNODES + w];
    len[ty] = rp[ty * NNODES + w + 1] - beg[ty];
  }
  int mx = max(max(len[0], len[1]), max(len[2], len[3]));
  float ax[4] = {0.f, 0.f, 0.f, 0.f}, ay[4] = {0.f, 0.f, 0.f, 0.f};
#pragma unroll 2
  for (int i = 0; i < mx; ++i) {
#pragma unroll
    for (int ty = 0; ty < 4; ++ty) {
      if (i < len[ty]) {
        int s = esrc_s[beg[ty] + i];
        ushort2 u = *(const ushort2*)(hbf + (size_t)s * DIM + lane * 2);
        ax[ty] += bf2f(u.x);
        ay[ty] += bf2f(u.y);
      }
    }
  }
#pragma unroll
  for (int ty = 0; ty < 4; ++ty) {
    unsigned int packed = ((unsigned int)f2bf(ay[ty]) << 16) | (unsigned int)f2bf(ax[ty]);
    __builtin_nontemporal_store(
        packed, (unsigned int*)(agg4 + (size_t)ty * NNODES * DIM + (size_t)w * DIM + lane * 2));
  }
}

// ---------------- K2 (split path): abf = sum_ty agg4[ty] @ W_ty ------------
__global__ __launch_bounds__(512, 2) void transform_kernel(const unsigned short* __restrict__ agg4,
                                                           const unsigned short* __restrict__ WeT,
                                                           unsigned short* __restrict__ abf) {
  __shared__ s16x8 lds[2][2048];
  const int t = threadIdx.x;
  const int wid = t >> 6, lane = t & 63;
  const int l15 = lane & 15, kg = lane >> 4;
  const int j0 = wid * 16, jb = j0 + kg * 4;

  s16x8 wf[4][4];
#pragma unroll
  for (int ty = 0; ty < 4; ++ty)
#pragma unroll
    for (int c = 0; c < 4; ++c)
      wf[ty][c] = *(const s16x8*)(WeT + (ty << 14) + ((j0 + l15) << 7) + c * 32 + kg * 8);

  int chk[4], lby[4];
#pragma unroll
  for (int i = 0; i < 4; ++i) {
    chk[i] = t + i * 512;
    int row = (chk[i] & 511) >> 4;
    int w16 = chk[i] & 15;
    lby[i] = (chk[i] >> 9) * 8192 + row * 256 + ((w16 ^ (row & 7)) << 4);
  }
  auto gsrc = [&](int i, int tile) -> const s16x8* {
    int ty = chk[i] >> 9;
    int row = (chk[i] & 511) >> 4;
    int w16 = chk[i] & 15;
    return (const s16x8*)(agg4 + (size_t)ty * NNODES * DIM +
                          (size_t)(tile * 32 + row) * DIM + w16 * 8);
  };

  int tile = blockIdx.x;
  if (tile >= NTILES) return;
  s16x8 st[4];
#pragma unroll
  for (int i = 0; i < 4; ++i) st[i] = __builtin_nontemporal_load(gsrc(i, tile));
#pragma unroll
  for (int i = 0; i < 4; ++i) *(s16x8*)((char*)&lds[0][0] + lby[i]) = st[i];
  int nx = tile + gridDim.x;
  bool hasnx = nx < NTILES;
  if (hasnx)
#pragma unroll
    for (int i = 0; i < 4; ++i) st[i] = __builtin_nontemporal_load(gsrc(i, nx));
  __syncthreads();
  int cur = 0;

  while (true) {
    if (hasnx) {
#pragma unroll
      for (int i = 0; i < 4; ++i) *(s16x8*)((char*)&lds[cur ^ 1][0] + lby[i]) = st[i];
    }
    int nx2 = nx + gridDim.x;
    bool has2 = hasnx && (nx2 < NTILES);
    if (has2) {
#pragma unroll
      for (int i = 0; i < 4; ++i) st[i] = __builtin_nontemporal_load(gsrc(i, nx2));
    }

    f32x4 acc[2] = {(f32x4){0.f, 0.f, 0.f, 0.f}, (f32x4){0.f, 0.f, 0.f, 0.f}};
    char* B0 = (char*)&lds[cur][0];
#pragma unroll
    for (int ty = 0; ty < 4; ++ty) {
#pragma unroll
      for (int c = 0; c < 4; ++c) {
        s16x8 afr[2];
#pragma unroll
        for (int nb = 0; nb < 2; ++nb) {
          int row = nb * 16 + l15;
          afr[nb] = *(const s16x8*)(B0 + ty * 8192 + row * 256 +
                                    ((c * 64 + kg * 16) ^ ((row & 7) << 4)));
        }
        acc[0] = MFMA(wf[ty][c], afr[0], acc[0]);
        acc[1] = MFMA(wf[ty][c], afr[1], acc[1]);
      }
    }
    const int n0 = tile * 32;
#pragma unroll
    for (int nb = 0; nb < 2; ++nb) {
      int n = n0 + nb * 16 + l15;
      ushort4 u = {f2bf(acc[nb][0]), f2bf(acc[nb][1]), f2bf(acc[nb][2]), f2bf(acc[nb][3])};
      *(ushort4*)(abf + (size_t)n * DIM + jb) = u;
    }
    __syncthreads();
    if (!hasnx) break;
    tile = nx;
    nx = nx2;
    hasnx = has2;
    cur ^= 1;
  }
}

// ---------------- fused path: msg2 = gather(8-seg interleave) + MFMA -------
// Persistent 512-thread blocks; per 32-node tile: phase A gathers with 8
// concurrent segments/wave (2 nodes x 4 types) x 2 passes into swizzled LDS
// (fp32 accum, bf16 store: bit-identical to split path); phase B = MFMA.
__global__ __launch_bounds__(512, 4) void msg2_kernel(const unsigned short* __restrict__ hbf,
                                                      const int* __restrict__ rp,
                                                      const int* __restrict__ esrc_s,
                                                      const unsigned short* __restrict__ WeT,
                                                      unsigned short* __restrict__ abf) {
  __shared__ char lds[32768];  // 4 planes x [32][128] bf16, 16B-chunk XOR-swizzled
  const int t = threadIdx.x;
  const int wid = t >> 6, lane = t & 63;
  const int l15 = lane & 15, kg = lane >> 4;
  const int j0 = wid * 16, jb = j0 + kg * 4;
  const int swz_w = lane >> 2;
  const int sub = (lane & 3) * 4;

  for (int tile = blockIdx.x; tile < NTILES; tile += gridDim.x) {
    const int n0 = tile * 32;
    // ---- Phase A: 2 passes x 8 interleaved segments ----
#pragma unroll
    for (int pass = 0; pass < 2; ++pass) {
      int beg[8], len[8];
#pragma unroll
      for (int s = 0; s < 8; ++s) {
        int node = n0 + wid * 4 + pass * 2 + (s >> 2);
        int idx = (s & 3) * NNODES + node;
        beg[s] = rp[idx];
        len[s] = rp[idx + 1] - beg[s];
      }
      int mx = 0;
#pragma unroll
      for (int s = 0; s < 8; ++s) mx = max(mx, len[s]);
      float ax[8] = {0.f, 0.f, 0.f, 0.f, 0.f, 0.f, 0.f, 0.f};
      float ay[8] = {0.f, 0.f, 0.f, 0.f, 0.f, 0.f, 0.f, 0.f};
      for (int i = 0; i < mx; ++i) {
#pragma unroll
        for (int s = 0; s < 8; ++s) {
          if (i < len[s]) {
            int src = esrc_s[beg[s] + i];
            ushort2 u = *(const ushort2*)(hbf + (size_t)src * DIM + lane * 2);
            ax[s] += bf2f(u.x);
            ay[s] += bf2f(u.y);
          }
        }
      }
#pragma unroll
      for (int s = 0; s < 8; ++s) {
        int row = wid * 4 + pass * 2 + (s >> 2);
        int lbase = row * 256 + ((swz_w ^ (row & 7)) << 4) + sub;
        unsigned int packed = ((unsigned int)f2bf(ay[s]) << 16) | (unsigned int)f2bf(ax[s]);
        *(unsigned int*)(lds + (s & 3) * 8192 + lbase) = packed;
      }
    }
    __syncthreads();

    // ---- Phase B: acc = sum_ty A_ty-tile @ W_ty ----
    f32x4 acc[2] = {(f32x4){0.f, 0.f, 0.f, 0.f}, (f32x4){0.f, 0.f, 0.f, 0.f}};
#pragma unroll
    for (int ty = 0; ty < 4; ++ty) {
#pragma unroll
      for (int c = 0; c < 4; ++c) {
        s16x8 wfr = *(const s16x8*)(WeT + (ty << 14) + ((j0 + l15) << 7) + c * 32 + kg * 8);
        s16x8 afr[2];
#pragma unroll
        for (int nb = 0; nb < 2; ++nb) {
          int row = nb * 16 + l15;
          afr[nb] = *(const s16x8*)(lds + ty * 8192 + row * 256 +
                                    ((c * 64 + kg * 16) ^ ((row & 7) << 4)));
        }
        acc[0] = MFMA(wfr, afr[0], acc[0]);
        acc[1] = MFMA(wfr, afr[1], acc[1]);
      }
    }
#pragma unroll
    for (int nb = 0; nb < 2; ++nb) {
      int n = n0 + nb * 16 + l15;
      ushort4 u = {f2bf(acc[nb][0]), f2bf(acc[nb][1]), f2bf(acc[nb][2]), f2bf(acc[nb][3])};
      *(ushort4*)(abf + (size_t)n * DIM + jb) = u;
    }
    __syncthreads();
  }
}

// ---------------- K3: fused GRU via MFMA (LDS-staged, pipelined) -----------
__global__ __launch_bounds__(512, 2) void gru_mfma_kernel(const unsigned short* __restrict__ abf,
                                                          unsigned short* __restrict__ hbf,
                                                          const unsigned short* __restrict__ Wih,
                                                          const unsigned short* __restrict__ Whh,
                                                          const float* __restrict__ b_ih,
                                                          const float* __restrict__ b_hh) {
  __shared__ s16x8 lds[2][1024];
  const int t = threadIdx.x;
  const int wid = t >> 6, lane = t & 63;
  const int l15 = lane & 15, kg = lane >> 4;
  const int j0 = wid * 16, jb = j0 + kg * 4;

  s16x8 wI[3][4], wH[3][4];
#pragma unroll
  for (int g = 0; g < 3; ++g)
#pragma unroll
    for (int c = 0; c < 4; ++c) {
      int jrow = g * 128 + j0 + l15;
      wI[g][c] = *(const s16x8*)(Wih + (jrow << 7) + c * 32 + kg * 8);
      wH[g][c] = *(const s16x8*)(Whh + (jrow << 7) + c * 32 + kg * 8);
    }
  float4 bir = *(const float4*)(b_ih + jb);
  float4 biz = *(const float4*)(b_ih + 128 + jb);
  float4 bin_ = *(const float4*)(b_ih + 256 + jb);
  float4 bhr = *(const float4*)(b_hh + jb);
  float4 bhz = *(const float4*)(b_hh + 128 + jb);
  float4 bhn = *(const float4*)(b_hh + 256 + jb);

  int chk0 = t, chk1 = t + 512;
  int row0 = (chk0 & 511) >> 4, w160 = chk0 & 15;
  int row1 = (chk1 & 511) >> 4, w161 = chk1 & 15;
  int lb0 = (chk0 >> 9) * 8192 + row0 * 256 + ((w160 ^ (row0 & 7)) << 4);
  int lb1 = (chk1 >> 9) * 8192 + row1 * 256 + ((w161 ^ (row1 & 7)) << 4);
  int hbyte_lo = (jb * 2) & 15;
  int hbyte_slot = (jb * 2) >> 4;

  int tile = blockIdx.x;
  if (tile >= NTILES) return;
  s16x8 st0, st1;
  st0 = *(const s16x8*)(((chk0 >> 9) ? hbf : abf) + (size_t)(tile * 32 + row0) * DIM + w160 * 8);
  st1 = *(const s16x8*)(((chk1 >> 9) ? hbf : abf) + (size_t)(tile * 32 + row1) * DIM + w161 * 8);
  *(s16x8*)((char*)&lds[0][0] + lb0) = st0;
  *(s16x8*)((char*)&lds[0][0] + lb1) = st1;
  int nx = tile + gridDim.x;
  bool hasnx = nx < NTILES;
  if (hasnx) {
    st0 = *(const s16x8*)(((chk0 >> 9) ? hbf : abf) + (size_t)(nx * 32 + row0) * DIM + w160 * 8);
    st1 = *(const s16x8*)(((chk1 >> 9) ? hbf : abf) + (size_t)(nx * 32 + row1) * DIM + w161 * 8);
  }
  __syncthreads();
  int cur = 0;

  while (true) {
    if (hasnx) {
      *(s16x8*)((char*)&lds[cur ^ 1][0] + lb0) = st0;
      *(s16x8*)((char*)&lds[cur ^ 1][0] + lb1) = st1;
    }
    int nx2 = nx + gridDim.x;
    bool has2 = hasnx && (nx2 < NTILES);
    if (has2) {
      st0 = *(const s16x8*)(((chk0 >> 9) ? hbf : abf) + (size_t)(nx2 * 32 + row0) * DIM + w160 * 8);
      st1 = *(const s16x8*)(((chk1 >> 9) ? hbf : abf) + (size_t)(nx2 * 32 + row1) * DIM + w161 * 8);
    }

    f32x4 gi[3][2], gh[3][2];
#pragma unroll
    for (int g = 0; g < 3; ++g)
#pragma unroll
      for (int nb = 0; nb < 2; ++nb) {
        gi[g][nb] = (f32x4){0.f, 0.f, 0.f, 0.f};
        gh[g][nb] = (f32x4){0.f, 0.f, 0.f, 0.f};
      }
    char* aB = (char*)&lds[cur][0];
    char* hB = aB + 8192;
#pragma unroll
    for (int c = 0; c < 4; ++c) {
      s16x8 afr[2], hfr[2];
#pragma unroll
      for (int nb = 0; nb < 2; ++nb) {
        int row = nb * 16 + l15;
        int off = row * 256 + ((c * 64 + kg * 16) ^ ((row & 7) << 4));
        afr[nb] = *(const s16x8*)(aB + off);
        hfr[nb] = *(const s16x8*)(hB + off);
      }
#pragma unroll
      for (int g = 0; g < 3; ++g) {
        gi[g][0] = MFMA(wI[g][c], afr[0], gi[g][0]);
        gi[g][1] = MFMA(wI[g][c], afr[1], gi[g][1]);
        gh[g][0] = MFMA(wH[g][c], hfr[0], gh[g][0]);
        gh[g][1] = MFMA(wH[g][c], hfr[1], gh[g][1]);
      }
    }

    const int n0 = tile * 32;
#pragma unroll
    for (int nb = 0; nb < 2; ++nb) {
      int row = nb * 16 + l15;
      int n = n0 + row;
      int hb = row * 256 + ((hbyte_slot << 4) ^ ((row & 7) << 4)) + hbyte_lo;
      ushort4 hold4 = *(const ushort4*)(hB + hb);
      ushort4 outu;
#pragma unroll
      for (int reg = 0; reg < 4; ++reg) {
        float ir = gi[0][nb][reg] + ((const float*)&bir)[reg];
        float iz = gi[1][nb][reg] + ((const float*)&biz)[reg];
        float in_ = gi[2][nb][reg] + ((const float*)&bin_)[reg];
        float hr = gh[0][nb][reg] + ((const float*)&bhr)[reg];
        float hz = gh[1][nb][reg] + ((const float*)&bhz)[reg];
        float hn = gh[2][nb][reg] + ((const float*)&bhn)[reg];
        float r = 1.f / (1.f + __expf(-(ir + hr)));
        float z = 1.f / (1.f + __expf(-(iz + hz)));
        float x = in_ + r * hn;
        float ex = __expf(2.f * x);
        float nn = 1.f - 2.f / (ex + 1.f);  // tanh
        float ho = bf2f(((const unsigned short*)&hold4)[reg]);
        float hv = (1.f - z) * nn + z * ho;
        ((unsigned short*)&outu)[reg] = f2bf(hv);
      }
      *(ushort4*)(hbf + (size_t)n * DIM + jb) = outu;
    }
    __syncthreads();
    if (!hasnx) break;
    tile = nx;
    nx = nx2;
    hasnx = has2;
    cur ^= 1;
  }
}

// ---------------- pooled[g] = sum_{gid[n]==g} h[n] ----------------
__global__ __launch_bounds__(128) void pool_kernel(const unsigned short* __restrict__ h,
                                                   const int* __restrict__ gid,
                                                   float* __restrict__ pooled) {
  int j = threadIdx.x;
  int n0 = blockIdx.x * 32;
  int end = n0 + 32;
  if (end > NNODES) end = NNODES;
  int cur = gid[n0];
  float acc = 0.f;
  for (int n = n0; n < end; ++n) {
    int g = gid[n];
    if (g != cur) {
      atomicAdd(&pooled[cur * DIM + j], acc);
      acc = 0.f;
      cur = g;
    }
    acc += bf2f(h[(size_t)n * DIM + j]);
  }
  atomicAdd(&pooled[cur * DIM + j], acc);
}

// ---------------- logits + sigmoid ----------------
__global__ __launch_bounds__(128) void cls_kernel(const float* __restrict__ pooled,
                                                  const float* __restrict__ Wc,
                                                  const float* __restrict__ bc,
                                                  float* __restrict__ out) {
  int g = threadIdx.x;
  float acc = bc[0];
  for (int k = 0; k < DIM; ++k) acc = fmaf(pooled[g * DIM + k], Wc[k], acc);
  out[g] = 1.f / (1.f + __expf(-acc));
}

extern "C" void kernel_launch(void* const* d_in, const int* in_sizes, int n_in,
                              void* d_out, int out_size, void* d_ws, size_t ws_size,
                              hipStream_t stream) {
  const float* features = (const float*)d_in[0];
  const int* esrc = (const int*)d_in[1];
  const int* edst = (const int*)d_in[2];
  const int* etyp = (const int*)d_in[3];
  const int* gids = (const int*)d_in[4];
  const float* W_edge = (const float*)d_in[5];
  const float* W_ih = (const float*)d_in[6];
  const float* W_hh = (const float*)d_in[7];
  const float* b_ih = (const float*)d_in[8];
  const float* b_hh = (const float*)d_in[9];
  const float* W_cls = (const float*)d_in[10];
  const float* b_cls = (const float*)d_in[11];
  float* out = (float*)d_out;

  const size_t nd = (size_t)NNODES * DIM;
  char* p = (char*)d_ws;
  auto take = [&](size_t bytes) {
    char* q = p;
    p += (bytes + 15) & ~(size_t)15;
    return (void*)q;
  };
  unsigned short* agg4 = (unsigned short*)take(NETYPES * nd * 2);  // 102.4 MB
  unsigned short* abf = (unsigned short*)take(nd * 2);             // 25.6 MB
  unsigned short* hbf = (unsigned short*)take(nd * 2);             // 25.6 MB
  unsigned short* WeT = (unsigned short*)take(NETYPES * DIM * DIM * 2);
  unsigned short* Wihb = (unsigned short*)take(384 * DIM * 2);
  unsigned short* Whhb = (unsigned short*)take(384 * DIM * 2);
  int* rp = (int*)take((NBINS + 1) * 4);
  int* cursor = (int*)take(NBINS * 4);
  int* bsum = (int*)take(512 * 4);
  int* boffs = (int*)take(512 * 4);
  int* esrc_s = (int*)take(NEDGES * 4);
  float* pooled = (float*)take(NGRAPHS * DIM * 4);
  size_t need = (size_t)(p - (char*)d_ws);

  if (ws_size < need) {
    fill_kernel<<<(out_size + 127) / 128, 128, 0, stream>>>(out, out_size, 0.5f);
    return;
  }

  cvt_h_kernel<<<(int)(nd / 4 + 255) / 256, 256, 0, stream>>>(features, hbf, (int)(nd / 4));
  cvt_we_kernel<<<(NETYPES * DIM * DIM + 255) / 256, 256, 0, stream>>>(W_edge, WeT);
  cvt_w_kernel<<<(384 * DIM + 255) / 256, 256, 0, stream>>>(W_ih, Wihb, 384 * DIM);
  cvt_w_kernel<<<(384 * DIM + 255) / 256, 256, 0, stream>>>(W_hh, Whhb, 384 * DIM);

  hipMemsetAsync(cursor, 0, (size_t)NBINS * 4, stream);
  hist_kernel<<<(NEDGES + 255) / 256, 256, 0, stream>>>(edst, etyp, cursor);
  scan1_kernel<<<SCAN_BLK, 256, 0, stream>>>(cursor, rp, bsum);
  scan2_kernel<<<1, 512, 0, stream>>>(bsum, boffs, rp);
  scan3_kernel<<<SCAN_BLK, 256, 0, stream>>>(rp, boffs);
  hipMemcpyAsync(cursor, rp, (size_t)NBINS * 4, hipMemcpyDeviceToDevice, stream);
  fill_edges_kernel<<<(NEDGES + 255) / 256, 256, 0, stream>>>(esrc, edst, etyp, cursor, esrc_s);

  for (int s = 0; s < NSTEPS; ++s) {
    if ((s & 1) == 0) {
      // fused path (A)
      msg2_kernel<<<PGRID, 512, 0, stream>>>(hbf, rp, esrc_s, WeT, abf);
    } else {
      // split path (B)
      agg4_ilv_kernel<<<(NNODES * 64 + 255) / 256, 256, 0, stream>>>(hbf, rp, esrc_s, agg4);
      transform_kernel<<<PGRID, 512, 0, stream>>>(agg4, WeT, abf);
    }
    gru_mfma_kernel<<<GRU_GRID, 512, 0, stream>>>(abf, hbf, Wihb, Whhb, b_ih, b_hh);
  }

  hipMemsetAsync(pooled, 0, (size_t)NGRAPHS * DIM * 4, stream);
  pool_kernel<<<(NNODES + 31) / 32, 128, 0, stream>>>(hbf, gids, pooled);
  cls_kernel<<<1, 128, 0, stream>>>(pooled, W_cls, b_cls, out);
}

// Round 13
// 1274.418 us; speedup vs baseline: 1.1993x; 1.1993x over previous
//
#include <hip/hip_runtime.h>
#include <cstdint>

#define NNODES 100000
#define NEDGES 600000
#define NETYPES 4
#define DIM 128
#define NSTEPS 8
#define NGRAPHS 128
#define NBINS (NETYPES * NNODES)
#define SCAN_BLK 391  // ceil(NBINS/1024)
#define NTILES (NNODES / 32)
#define PGRID 512
#define GRU_GRID 512

typedef short s16x8 __attribute__((ext_vector_type(8)));
typedef float f32x4 __attribute__((ext_vector_type(4)));

#define MFMA(a, b, c) __builtin_amdgcn_mfma_f32_16x16x32_bf16(a, b, c, 0, 0, 0)

static __device__ inline unsigned short f2bf(float x) {
  unsigned int u = __float_as_uint(x);
  unsigned int r = (u + 0x7FFFu + ((u >> 16) & 1u)) >> 16;
  return (unsigned short)r;
}
static __device__ inline float bf2f(unsigned short b) {
  return __uint_as_float(((unsigned int)b) << 16);
}

// ---------------- diagnostic fill ----------------
__global__ __launch_bounds__(128) void fill_kernel(float* __restrict__ out, int n, float v) {
  int i = blockIdx.x * 128 + threadIdx.x;
  if (i < n) out[i] = v;
}

// ---------------- fp32 -> bf16 converts ----------------
__global__ __launch_bounds__(256) void cvt_h_kernel(const float* __restrict__ f,
                                                    unsigned short* __restrict__ h, int n4) {
  int i = blockIdx.x * 256 + threadIdx.x;
  if (i < n4) {
    float4 v = ((const float4*)f)[i];
    ushort4 u = {f2bf(v.x), f2bf(v.y), f2bf(v.z), f2bf(v.w)};
    ((ushort4*)h)[i] = u;
  }
}

// W_edge [e][d][h] fp32 -> WeT [e][h][d] bf16 (j-major, k-contiguous)
__global__ __launch_bounds__(256) void cvt_we_kernel(const float* __restrict__ W,
                                                     unsigned short* __restrict__ WT) {
  int i = blockIdx.x * 256 + threadIdx.x;
  if (i < NETYPES * DIM * DIM) {
    int e = i >> 14;
    int r = i & 16383;
    int d = r >> 7;   // k
    int j = r & 127;  // output col
    WT[(e << 14) + (j << 7) + d] = f2bf(W[i]);
  }
}

__global__ __launch_bounds__(256) void cvt_w_kernel(const float* __restrict__ W,
                                                    unsigned short* __restrict__ Wb, int n) {
  int i = blockIdx.x * 256 + threadIdx.x;
  if (i < n) Wb[i] = f2bf(W[i]);
}

// ---------------- CSR build: histogram / scan / fill ----------------
__global__ __launch_bounds__(256) void hist_kernel(const int* __restrict__ edst,
                                                   const int* __restrict__ etyp,
                                                   int* __restrict__ bins) {
  int e = blockIdx.x * 256 + threadIdx.x;
  if (e < NEDGES) atomicAdd(&bins[etyp[e] * NNODES + edst[e]], 1);
}

__global__ __launch_bounds__(256) void scan1_kernel(const int* __restrict__ bins,
                                                    int* __restrict__ rp,
                                                    int* __restrict__ bsum) {
  __shared__ int sh[256];
  int b = blockIdx.x, t = threadIdx.x;
  int base = b * 1024 + t * 4;
  int v0 = 0, v1 = 0, v2 = 0, v3 = 0;
  if (base + 3 < NBINS) {
    int4 q = *(const int4*)(bins + base);
    v0 = q.x; v1 = q.y; v2 = q.z; v3 = q.w;
  } else {
    if (base < NBINS) v0 = bins[base];
    if (base + 1 < NBINS) v1 = bins[base + 1];
    if (base + 2 < NBINS) v2 = bins[base + 2];
  }
  int s = v0 + v1 + v2 + v3;
  sh[t] = s;
  __syncthreads();
  for (int off = 1; off < 256; off <<= 1) {
    int x = (t >= off) ? sh[t - off] : 0;
    __syncthreads();
    if (t >= off) sh[t] += x;
    __syncthreads();
  }
  int run = sh[t] - s;
  if (t == 255) bsum[b] = sh[255];
  if (base < NBINS) rp[base] = run;
  run += v0;
  if (base + 1 < NBINS) rp[base + 1] = run;
  run += v1;
  if (base + 2 < NBINS) rp[base + 2] = run;
  run += v2;
  if (base + 3 < NBINS) rp[base + 3] = run;
}

__global__ __launch_bounds__(512) void scan2_kernel(const int* __restrict__ bsum,
                                                    int* __restrict__ boffs,
                                                    int* __restrict__ rp) {
  __shared__ int sh[512];
  int t = threadIdx.x;
  int v = (t < SCAN_BLK) ? bsum[t] : 0;
  sh[t] = v;
  __syncthreads();
  for (int off = 1; off < 512; off <<= 1) {
    int x = (t >= off) ? sh[t - off] : 0;
    __syncthreads();
    if (t >= off) sh[t] += x;
    __syncthreads();
  }
  if (t < SCAN_BLK) boffs[t] = sh[t] - v;
  if (t == SCAN_BLK - 1) rp[NBINS] = sh[t];
}

__global__ __launch_bounds__(256) void scan3_kernel(int* __restrict__ rp,
                                                    const int* __restrict__ boffs) {
  int b = blockIdx.x, t = threadIdx.x;
  int base = b * 1024 + t * 4;
  int off = boffs[b];
#pragma unroll
  for (int i = 0; i < 4; ++i)
    if (base + i < NBINS) rp[base + i] += off;
}

__global__ __launch_bounds__(256) void fill_edges_kernel(const int* __restrict__ esrc,
                                                         const int* __restrict__ edst,
                                                         const int* __restrict__ etyp,
                                                         int* __restrict__ cursor,
                                                         int* __restrict__ esrc_s) {
  int e = blockIdx.x * 256 + threadIdx.x;
  if (e < NEDGES) {
    int slot = atomicAdd(&cursor[etyp[e] * NNODES + edst[e]], 1);
    esrc_s[slot] = esrc[e];
  }
}

// ---------------- K1 variant A: one node per 32-lane HALF-wave -------------
// ushort4/lane covers the 256B row; 2 nodes share one instruction stream ->
// 8 independent gather streams in flight per wave, half the instructions.
// Per-(col,ty,node) accumulation order identical to agg4_ilv -> bit-identical.
__global__ __launch_bounds__(256) void agg4_half_kernel(const unsigned short* __restrict__ hbf,
                                                        const int* __restrict__ rp,
                                                        const int* __restrict__ esrc_s,
                                                        unsigned short* __restrict__ agg4) {
  int w = (blockIdx.x * 256 + threadIdx.x) >> 5;  // node = half-wave id
  int l32 = threadIdx.x & 31;                     // 4 cols per lane
  if (w >= NNODES) return;
  int beg[4], len[4];
#pragma unroll
  for (int ty = 0; ty < 4; ++ty) {
    beg[ty] = rp[ty * NNODES + w];
    len[ty] = rp[ty * NNODES + w + 1] - beg[ty];
  }
  int mx = max(max(len[0], len[1]), max(len[2], len[3]));
  float ac[4][4];
#pragma unroll
  for (int ty = 0; ty < 4; ++ty)
#pragma unroll
    for (int q = 0; q < 4; ++q) ac[ty][q] = 0.f;
#pragma unroll 2
  for (int i = 0; i < mx; ++i) {
#pragma unroll
    for (int ty = 0; ty < 4; ++ty) {
      if (i < len[ty]) {
        int s = esrc_s[beg[ty] + i];
        ushort4 u = *(const ushort4*)(hbf + (size_t)s * DIM + l32 * 4);
        ac[ty][0] += bf2f(u.x);
        ac[ty][1] += bf2f(u.y);
        ac[ty][2] += bf2f(u.z);
        ac[ty][3] += bf2f(u.w);
      }
    }
  }
#pragma unroll
  for (int ty = 0; ty < 4; ++ty) {
    unsigned long long packed =
        (unsigned long long)f2bf(ac[ty][0]) | ((unsigned long long)f2bf(ac[ty][1]) << 16) |
        ((unsigned long long)f2bf(ac[ty][2]) << 32) | ((unsigned long long)f2bf(ac[ty][3]) << 48);
    __builtin_nontemporal_store(
        packed,
        (unsigned long long*)(agg4 + (size_t)ty * NNODES * DIM + (size_t)w * DIM + l32 * 4));
  }
}

// ---------------- K1 variant B: 4-way interleaved, full wave (R10) ---------
__global__ __launch_bounds__(256) void agg4_ilv_kernel(const unsigned short* __restrict__ hbf,
                                                       const int* __restrict__ rp,
                                                       const int* __restrict__ esrc_s,
                                                       unsigned short* __restrict__ agg4) {
  int w = (blockIdx.x * 256 + threadIdx.x) >> 6;
  int lane = threadIdx.x & 63;
  if (w >= NNODES) return;
  int beg[4], len[4];
#pragma unroll
  for (int ty = 0; ty < 4; ++ty) {
    beg[ty] = rp[ty * NNODES + w];
    len[ty] = rp[ty * NNODES + w + 1] - beg[ty];
  }
  int mx = max(max(len[0], len[1]), max(len[2], len[3]));
  float ax[4] = {0.f, 0.f, 0.f, 0.f}, ay[4] = {0.f, 0.f, 0.f, 0.f};
#pragma unroll 2
  for (int i = 0; i < mx; ++i) {
#pragma unroll
    for (int ty = 0; ty < 4; ++ty) {
      if (i < len[ty]) {
        int s = esrc_s[beg[ty] + i];
        ushort2 u = *(const ushort2*)(hbf + (size_t)s * DIM + lane * 2);
        ax[ty] += bf2f(u.x);
        ay[ty] += bf2f(u.y);
      }
    }
  }
#pragma unroll
  for (int ty = 0; ty < 4; ++ty) {
    unsigned int packed = ((unsigned int)f2bf(ay[ty]) << 16) | (unsigned int)f2bf(ax[ty]);
    __builtin_nontemporal_store(
        packed, (unsigned int*)(agg4 + (size_t)ty * NNODES * DIM + (size_t)w * DIM + lane * 2));
  }
}

// ---------------- K2: abf = sum_ty agg4[ty] @ W_ty  (LDS-staged, pipelined)
__global__ __launch_bounds__(512, 2) void transform_kernel(const unsigned short* __restrict__ agg4,
                                                           const unsigned short* __restrict__ WeT,
                                                           unsigned short* __restrict__ abf) {
  __shared__ s16x8 lds[2][2048];
  const int t = threadIdx.x;
  const int wid = t >> 6, lane = t & 63;
  const int l15 = lane & 15, kg = lane >> 4;
  const int j0 = wid * 16, jb = j0 + kg * 4;

  s16x8 wf[4][4];
#pragma unroll
  for (int ty = 0; ty < 4; ++ty)
#pragma unroll
    for (int c = 0; c < 4; ++c)
      wf[ty][c] = *(const s16x8*)(WeT + (ty << 14) + ((j0 + l15) << 7) + c * 32 + kg * 8);

  int chk[4], lby[4];
#pragma unroll
  for (int i = 0; i < 4; ++i) {
    chk[i] = t + i * 512;
    int row = (chk[i] & 511) >> 4;
    int w16 = chk[i] & 15;
    lby[i] = (chk[i] >> 9) * 8192 + row * 256 + ((w16 ^ (row & 7)) << 4);
  }
  auto gsrc = [&](int i, int tile) -> const s16x8* {
    int ty = chk[i] >> 9;
    int row = (chk[i] & 511) >> 4;
    int w16 = chk[i] & 15;
    return (const s16x8*)(agg4 + (size_t)ty * NNODES * DIM +
                          (size_t)(tile * 32 + row) * DIM + w16 * 8);
  };

  int tile = blockIdx.x;
  if (tile >= NTILES) return;
  s16x8 st[4];
#pragma unroll
  for (int i = 0; i < 4; ++i) st[i] = __builtin_nontemporal_load(gsrc(i, tile));
#pragma unroll
  for (int i = 0; i < 4; ++i) *(s16x8*)((char*)&lds[0][0] + lby[i]) = st[i];
  int nx = tile + gridDim.x;
  bool hasnx = nx < NTILES;
  if (hasnx)
#pragma unroll
    for (int i = 0; i < 4; ++i) st[i] = __builtin_nontemporal_load(gsrc(i, nx));
  __syncthreads();
  int cur = 0;

  while (true) {
    if (hasnx) {
#pragma unroll
      for (int i = 0; i < 4; ++i) *(s16x8*)((char*)&lds[cur ^ 1][0] + lby[i]) = st[i];
    }
    int nx2 = nx + gridDim.x;
    bool has2 = hasnx && (nx2 < NTILES);
    if (has2) {
#pragma unroll
      for (int i = 0; i < 4; ++i) st[i] = __builtin_nontemporal_load(gsrc(i, nx2));
    }

    f32x4 acc[2] = {(f32x4){0.f, 0.f, 0.f, 0.f}, (f32x4){0.f, 0.f, 0.f, 0.f}};
    char* B0 = (char*)&lds[cur][0];
#pragma unroll
    for (int ty = 0; ty < 4; ++ty) {
#pragma unroll
      for (int c = 0; c < 4; ++c) {
        s16x8 afr[2];
#pragma unroll
        for (int nb = 0; nb < 2; ++nb) {
          int row = nb * 16 + l15;
          afr[nb] = *(const s16x8*)(B0 + ty * 8192 + row * 256 +
                                    ((c * 64 + kg * 16) ^ ((row & 7) << 4)));
        }
        acc[0] = MFMA(wf[ty][c], afr[0], acc[0]);
        acc[1] = MFMA(wf[ty][c], afr[1], acc[1]);
      }
    }
    const int n0 = tile * 32;
#pragma unroll
    for (int nb = 0; nb < 2; ++nb) {
      int n = n0 + nb * 16 + l15;
      ushort4 u = {f2bf(acc[nb][0]), f2bf(acc[nb][1]), f2bf(acc[nb][2]), f2bf(acc[nb][3])};
      *(ushort4*)(abf + (size_t)n * DIM + jb) = u;
    }
    __syncthreads();
    if (!hasnx) break;
    tile = nx;
    nx = nx2;
    hasnx = has2;
    cur ^= 1;
  }
}

// ---------------- K3: fused GRU via MFMA (LDS-staged, pipelined) -----------
__global__ __launch_bounds__(512, 2) void gru_mfma_kernel(const unsigned short* __restrict__ abf,
                                                          unsigned short* __restrict__ hbf,
                                                          const unsigned short* __restrict__ Wih,
                                                          const unsigned short* __restrict__ Whh,
                                                          const float* __restrict__ b_ih,
                                                          const float* __restrict__ b_hh) {
  __shared__ s16x8 lds[2][1024];
  const int t = threadIdx.x;
  const int wid = t >> 6, lane = t & 63;
  const int l15 = lane & 15, kg = lane >> 4;
  const int j0 = wid * 16, jb = j0 + kg * 4;

  s16x8 wI[3][4], wH[3][4];
#pragma unroll
  for (int g = 0; g < 3; ++g)
#pragma unroll
    for (int c = 0; c < 4; ++c) {
      int jrow = g * 128 + j0 + l15;
      wI[g][c] = *(const s16x8*)(Wih + (jrow << 7) + c * 32 + kg * 8);
      wH[g][c] = *(const s16x8*)(Whh + (jrow << 7) + c * 32 + kg * 8);
    }
  float4 bir = *(const float4*)(b_ih + jb);
  float4 biz = *(const float4*)(b_ih + 128 + jb);
  float4 bin_ = *(const float4*)(b_ih + 256 + jb);
  float4 bhr = *(const float4*)(b_hh + jb);
  float4 bhz = *(const float4*)(b_hh + 128 + jb);
  float4 bhn = *(const float4*)(b_hh + 256 + jb);

  int chk0 = t, chk1 = t + 512;
  int row0 = (chk0 & 511) >> 4, w160 = chk0 & 15;
  int row1 = (chk1 & 511) >> 4, w161 = chk1 & 15;
  int lb0 = (chk0 >> 9) * 8192 + row0 * 256 + ((w160 ^ (row0 & 7)) << 4);
  int lb1 = (chk1 >> 9) * 8192 + row1 * 256 + ((w161 ^ (row1 & 7)) << 4);
  int hbyte_lo = (jb * 2) & 15;
  int hbyte_slot = (jb * 2) >> 4;

  int tile = blockIdx.x;
  if (tile >= NTILES) return;
  s16x8 st0, st1;
  st0 = *(const s16x8*)(((chk0 >> 9) ? hbf : abf) + (size_t)(tile * 32 + row0) * DIM + w160 * 8);
  st1 = *(const s16x8*)(((chk1 >> 9) ? hbf : abf) + (size_t)(tile * 32 + row1) * DIM + w161 * 8);
  *(s16x8*)((char*)&lds[0][0] + lb0) = st0;
  *(s16x8*)((char*)&lds[0][0] + lb1) = st1;
  int nx = tile + gridDim.x;
  bool hasnx = nx < NTILES;
  if (hasnx) {
    st0 = *(const s16x8*)(((chk0 >> 9) ? hbf : abf) + (size_t)(nx * 32 + row0) * DIM + w160 * 8);
    st1 = *(const s16x8*)(((chk1 >> 9) ? hbf : abf) + (size_t)(nx * 32 + row1) * DIM + w161 * 8);
  }
  __syncthreads();
  int cur = 0;

  while (true) {
    if (hasnx) {
      *(s16x8*)((char*)&lds[cur ^ 1][0] + lb0) = st0;
      *(s16x8*)((char*)&lds[cur ^ 1][0] + lb1) = st1;
    }
    int nx2 = nx + gridDim.x;
    bool has2 = hasnx && (nx2 < NTILES);
    if (has2) {
      st0 = *(const s16x8*)(((chk0 >> 9) ? hbf : abf) + (size_t)(nx2 * 32 + row0) * DIM + w160 * 8);
      st1 = *(const s16x8*)(((chk1 >> 9) ? hbf : abf) + (size_t)(nx2 * 32 + row1) * DIM + w161 * 8);
    }

    f32x4 gi[3][2], gh[3][2];
#pragma unroll
    for (int g = 0; g < 3; ++g)
#pragma unroll
      for (int nb = 0; nb < 2; ++nb) {
        gi[g][nb] = (f32x4){0.f, 0.f, 0.f, 0.f};
        gh[g][nb] = (f32x4){0.f, 0.f, 0.f, 0.f};
      }
    char* aB = (char*)&lds[cur][0];
    char* hB = aB + 8192;
#pragma unroll
    for (int c = 0; c < 4; ++c) {
      s16x8 afr[2], hfr[2];
#pragma unroll
      for (int nb = 0; nb < 2; ++nb) {
        int row = nb * 16 + l15;
        int off = row * 256 + ((c * 64 + kg * 16) ^ ((row & 7) << 4));
        afr[nb] = *(const s16x8*)(aB + off);
        hfr[nb] = *(const s16x8*)(hB + off);
      }
#pragma unroll
      for (int g = 0; g < 3; ++g) {
        gi[g][0] = MFMA(wI[g][c], afr[0], gi[g][0]);
        gi[g][1] = MFMA(wI[g][c], afr[1], gi[g][1]);
        gh[g][0] = MFMA(wH[g][c], hfr[0], gh[g][0]);
        gh[g][1] = MFMA(wH[g][c], hfr[1], gh[g][1]);
      }
    }

    const int n0 = tile * 32;
#pragma unroll
    for (int nb = 0; nb < 2; ++nb) {
      int row = nb * 16 + l15;
      int n = n0 + row;
      int hb = row * 256 + ((hbyte_slot << 4) ^ ((row & 7) << 4)) + hbyte_lo;
      ushort4 hold4 = *(const ushort4*)(hB + hb);
      ushort4 outu;
#pragma unroll
      for (int reg = 0; reg < 4; ++reg) {
        float ir = gi[0][nb][reg] + ((const float*)&bir)[reg];
        float iz = gi[1][nb][reg] + ((const float*)&biz)[reg];
        float in_ = gi[2][nb][reg] + ((const float*)&bin_)[reg];
        float hr = gh[0][nb][reg] + ((const float*)&bhr)[reg];
        float hz = gh[1][nb][reg] + ((const float*)&bhz)[reg];
        float hn = gh[2][nb][reg] + ((const float*)&bhn)[reg];
        float r = 1.f / (1.f + __expf(-(ir + hr)));
        float z = 1.f / (1.f + __expf(-(iz + hz)));
        float x = in_ + r * hn;
        float ex = __expf(2.f * x);
        float nn = 1.f - 2.f / (ex + 1.f);  // tanh
        float ho = bf2f(((const unsigned short*)&hold4)[reg]);
        float hv = (1.f - z) * nn + z * ho;
        ((unsigned short*)&outu)[reg] = f2bf(hv);
      }
      *(ushort4*)(hbf + (size_t)n * DIM + jb) = outu;
    }
    __syncthreads();
    if (!hasnx) break;
    tile = nx;
    nx = nx2;
    hasnx = has2;
    cur ^= 1;
  }
}

// ---------------- pooled[g] = sum_{gid[n]==g} h[n] ----------------
__global__ __launch_bounds__(128) void pool_kernel(const unsigned short* __restrict__ h,
                                                   const int* __restrict__ gid,
                                                   float* __restrict__ pooled) {
  int j = threadIdx.x;
  int n0 = blockIdx.x * 32;
  int end = n0 + 32;
  if (end > NNODES) end = NNODES;
  int cur = gid[n0];
  float acc = 0.f;
  for (int n = n0; n < end; ++n) {
    int g = gid[n];
    if (g != cur) {
      atomicAdd(&pooled[cur * DIM + j], acc);
      acc = 0.f;
      cur = g;
    }
    acc += bf2f(h[(size_t)n * DIM + j]);
  }
  atomicAdd(&pooled[cur * DIM + j], acc);
}

// ---------------- logits + sigmoid ----------------
__global__ __launch_bounds__(128) void cls_kernel(const float* __restrict__ pooled,
                                                  const float* __restrict__ Wc,
                                                  const float* __restrict__ bc,
                                                  float* __restrict__ out) {
  int g = threadIdx.x;
  float acc = bc[0];
  for (int k = 0; k < DIM; ++k) acc = fmaf(pooled[g * DIM + k], Wc[k], acc);
  out[g] = 1.f / (1.f + __expf(-acc));
}

extern "C" void kernel_launch(void* const* d_in, const int* in_sizes, int n_in,
                              void* d_out, int out_size, void* d_ws, size_t ws_size,
                              hipStream_t stream) {
  const float* features = (const float*)d_in[0];
  const int* esrc = (const int*)d_in[1];
  const int* edst = (const int*)d_in[2];
  const int* etyp = (const int*)d_in[3];
  const int* gids = (const int*)d_in[4];
  const float* W_edge = (const float*)d_in[5];
  const float* W_ih = (const float*)d_in[6];
  const float* W_hh = (const float*)d_in[7];
  const float* b_ih = (const float*)d_in[8];
  const float* b_hh = (const float*)d_in[9];
  const float* W_cls = (const float*)d_in[10];
  const float* b_cls = (const float*)d_in[11];
  float* out = (float*)d_out;

  const size_t nd = (size_t)NNODES * DIM;
  char* p = (char*)d_ws;
  auto take = [&](size_t bytes) {
    char* q = p;
    p += (bytes + 15) & ~(size_t)15;
    return (void*)q;
  };
  unsigned short* agg4 = (unsigned short*)take(NETYPES * nd * 2);  // 102.4 MB
  unsigned short* abf = (unsigned short*)take(nd * 2);             // 25.6 MB
  unsigned short* hbf = (unsigned short*)take(nd * 2);             // 25.6 MB
  unsigned short* WeT = (unsigned short*)take(NETYPES * DIM * DIM * 2);
  unsigned short* Wihb = (unsigned short*)take(384 * DIM * 2);
  unsigned short* Whhb = (unsigned short*)take(384 * DIM * 2);
  int* rp = (int*)take((NBINS + 1) * 4);
  int* cursor = (int*)take(NBINS * 4);
  int* bsum = (int*)take(512 * 4);
  int* boffs = (int*)take(512 * 4);
  int* esrc_s = (int*)take(NEDGES * 4);
  float* pooled = (float*)take(NGRAPHS * DIM * 4);
  size_t need = (size_t)(p - (char*)d_ws);

  if (ws_size < need) {
    fill_kernel<<<(out_size + 127) / 128, 128, 0, stream>>>(out, out_size, 0.5f);
    return;
  }

  cvt_h_kernel<<<(int)(nd / 4 + 255) / 256, 256, 0, stream>>>(features, hbf, (int)(nd / 4));
  cvt_we_kernel<<<(NETYPES * DIM * DIM + 255) / 256, 256, 0, stream>>>(W_edge, WeT);
  cvt_w_kernel<<<(384 * DIM + 255) / 256, 256, 0, stream>>>(W_ih, Wihb, 384 * DIM);
  cvt_w_kernel<<<(384 * DIM + 255) / 256, 256, 0, stream>>>(W_hh, Whhb, 384 * DIM);

  hipMemsetAsync(cursor, 0, (size_t)NBINS * 4, stream);
  hist_kernel<<<(NEDGES + 255) / 256, 256, 0, stream>>>(edst, etyp, cursor);
  scan1_kernel<<<SCAN_BLK, 256, 0, stream>>>(cursor, rp, bsum);
  scan2_kernel<<<1, 512, 0, stream>>>(bsum, boffs, rp);
  scan3_kernel<<<SCAN_BLK, 256, 0, stream>>>(rp, boffs);
  hipMemcpyAsync(cursor, rp, (size_t)NBINS * 4, hipMemcpyDeviceToDevice, stream);
  fill_edges_kernel<<<(NEDGES + 255) / 256, 256, 0, stream>>>(esrc, edst, etyp, cursor, esrc_s);

  for (int s = 0; s < NSTEPS; ++s) {
    if ((s & 1) == 0)
      agg4_half_kernel<<<(NNODES * 32 + 255) / 256, 256, 0, stream>>>(hbf, rp, esrc_s, agg4);
    else
      agg4_ilv_kernel<<<(NNODES * 64 + 255) / 256, 256, 0, stream>>>(hbf, rp, esrc_s, agg4);
    transform_kernel<<<PGRID, 512, 0, stream>>>(agg4, WeT, abf);
    gru_mfma_kernel<<<GRU_GRID, 512, 0, stream>>>(abf, hbf, Wihb, Whhb, b_ih, b_hh);
  }

  hipMemsetAsync(pooled, 0, (size_t)NGRAPHS * DIM * 4, stream);
  pool_kernel<<<(NNODES + 31) / 32, 128, 0, stream>>>(hbf, gids, pooled);
  cls_kernel<<<1, 128, 0, stream>>>(pooled, W_cls, b_cls, out);
}

// Round 14
// 1158.294 us; speedup vs baseline: 1.3196x; 1.1003x over previous
//
#include <hip/hip_runtime.h>
#include <cstdint>

#define NNODES 100000
#define NEDGES 600000
#define NETYPES 4
#define DIM 128
#define NSTEPS 8
#define NGRAPHS 128
#define NBINS (NETYPES * NNODES)
#define SCAN_BLK 391  // ceil(NBINS/1024)
#define NTILES (NNODES / 32)
#define PGRID 512
#define GRU_GRID 512

typedef short s16x8 __attribute__((ext_vector_type(8)));
typedef float f32x4 __attribute__((ext_vector_type(4)));

#define MFMA(a, b, c) __builtin_amdgcn_mfma_f32_16x16x32_bf16(a, b, c, 0, 0, 0)

static __device__ inline unsigned short f2bf(float x) {
  unsigned int u = __float_as_uint(x);
  unsigned int r = (u + 0x7FFFu + ((u >> 16) & 1u)) >> 16;
  return (unsigned short)r;
}
static __device__ inline float bf2f(unsigned short b) {
  return __uint_as_float(((unsigned int)b) << 16);
}

// ---------------- diagnostic fill ----------------
__global__ __launch_bounds__(128) void fill_kernel(float* __restrict__ out, int n, float v) {
  int i = blockIdx.x * 128 + threadIdx.x;
  if (i < n) out[i] = v;
}

// ---------------- fp32 -> bf16 converts ----------------
__global__ __launch_bounds__(256) void cvt_h_kernel(const float* __restrict__ f,
                                                    unsigned short* __restrict__ h, int n4) {
  int i = blockIdx.x * 256 + threadIdx.x;
  if (i < n4) {
    float4 v = ((const float4*)f)[i];
    ushort4 u = {f2bf(v.x), f2bf(v.y), f2bf(v.z), f2bf(v.w)};
    ((ushort4*)h)[i] = u;
  }
}

// W_edge [e][d][h] fp32 -> WeT [e][h][d] bf16 (j-major, k-contiguous)
__global__ __launch_bounds__(256) void cvt_we_kernel(const float* __restrict__ W,
                                                     unsigned short* __restrict__ WT) {
  int i = blockIdx.x * 256 + threadIdx.x;
  if (i < NETYPES * DIM * DIM) {
    int e = i >> 14;
    int r = i & 16383;
    int d = r >> 7;   // k
    int j = r & 127;  // output col
    WT[(e << 14) + (j << 7) + d] = f2bf(W[i]);
  }
}

__global__ __launch_bounds__(256) void cvt_w_kernel(const float* __restrict__ W,
                                                    unsigned short* __restrict__ Wb, int n) {
  int i = blockIdx.x * 256 + threadIdx.x;
  if (i < n) Wb[i] = f2bf(W[i]);
}

// ---------------- CSR build: histogram / scan / fill ----------------
__global__ __launch_bounds__(256) void hist_kernel(const int* __restrict__ edst,
                                                   const int* __restrict__ etyp,
                                                   int* __restrict__ bins) {
  int e = blockIdx.x * 256 + threadIdx.x;
  if (e < NEDGES) atomicAdd(&bins[etyp[e] * NNODES + edst[e]], 1);
}

__global__ __launch_bounds__(256) void scan1_kernel(const int* __restrict__ bins,
                                                    int* __restrict__ rp,
                                                    int* __restrict__ bsum) {
  __shared__ int sh[256];
  int b = blockIdx.x, t = threadIdx.x;
  int base = b * 1024 + t * 4;
  int v0 = 0, v1 = 0, v2 = 0, v3 = 0;
  if (base + 3 < NBINS) {
    int4 q = *(const int4*)(bins + base);
    v0 = q.x; v1 = q.y; v2 = q.z; v3 = q.w;
  } else {
    if (base < NBINS) v0 = bins[base];
    if (base + 1 < NBINS) v1 = bins[base + 1];
    if (base + 2 < NBINS) v2 = bins[base + 2];
  }
  int s = v0 + v1 + v2 + v3;
  sh[t] = s;
  __syncthreads();
  for (int off = 1; off < 256; off <<= 1) {
    int x = (t >= off) ? sh[t - off] : 0;
    __syncthreads();
    if (t >= off) sh[t] += x;
    __syncthreads();
  }
  int run = sh[t] - s;
  if (t == 255) bsum[b] = sh[255];
  if (base < NBINS) rp[base] = run;
  run += v0;
  if (base + 1 < NBINS) rp[base + 1] = run;
  run += v1;
  if (base + 2 < NBINS) rp[base + 2] = run;
  run += v2;
  if (base + 3 < NBINS) rp[base + 3] = run;
}

__global__ __launch_bounds__(512) void scan2_kernel(const int* __restrict__ bsum,
                                                    int* __restrict__ boffs,
                                                    int* __restrict__ rp) {
  __shared__ int sh[512];
  int t = threadIdx.x;
  int v = (t < SCAN_BLK) ? bsum[t] : 0;
  sh[t] = v;
  __syncthreads();
  for (int off = 1; off < 512; off <<= 1) {
    int x = (t >= off) ? sh[t - off] : 0;
    __syncthreads();
    if (t >= off) sh[t] += x;
    __syncthreads();
  }
  if (t < SCAN_BLK) boffs[t] = sh[t] - v;
  if (t == SCAN_BLK - 1) rp[NBINS] = sh[t];
}

__global__ __launch_bounds__(256) void scan3_kernel(int* __restrict__ rp,
                                                    const int* __restrict__ boffs) {
  int b = blockIdx.x, t = threadIdx.x;
  int base = b * 1024 + t * 4;
  int off = boffs[b];
#pragma unroll
  for (int i = 0; i < 4; ++i)
    if (base + i < NBINS) rp[base + i] += off;
}

__global__ __launch_bounds__(256) void fill_edges_kernel(const int* __restrict__ esrc,
                                                         const int* __restrict__ edst,
                                                         const int* __restrict__ etyp,
                                                         int* __restrict__ cursor,
                                                         int* __restrict__ esrc_s) {
  int e = blockIdx.x * 256 + threadIdx.x;
  if (e < NEDGES) {
    int slot = atomicAdd(&cursor[etyp[e] * NNODES + edst[e]], 1);
    esrc_s[slot] = esrc[e];
  }
}

// ---------------- K1 variant A: one node per 16-lane QUARTER-wave ----------
// s16x8/lane covers the 256B row with 16 lanes; 4 nodes share one instruction
// stream -> 16 independent gather streams in flight per wave.
__global__ __launch_bounds__(256) void agg4_quart_kernel(const unsigned short* __restrict__ hbf,
                                                         const int* __restrict__ rp,
                                                         const int* __restrict__ esrc_s,
                                                         unsigned short* __restrict__ agg4) {
  int w = (blockIdx.x * 256 + threadIdx.x) >> 4;  // node = quarter-wave id
  int l16 = threadIdx.x & 15;                     // 8 cols per lane
  if (w >= NNODES) return;
  int beg[4], len[4];
#pragma unroll
  for (int ty = 0; ty < 4; ++ty) {
    beg[ty] = rp[ty * NNODES + w];
    len[ty] = rp[ty * NNODES + w + 1] - beg[ty];
  }
  int mx = max(max(len[0], len[1]), max(len[2], len[3]));
  float ac[4][8];
#pragma unroll
  for (int ty = 0; ty < 4; ++ty)
#pragma unroll
    for (int q = 0; q < 8; ++q) ac[ty][q] = 0.f;
#pragma unroll 2
  for (int i = 0; i < mx; ++i) {
#pragma unroll
    for (int ty = 0; ty < 4; ++ty) {
      if (i < len[ty]) {
        int s = esrc_s[beg[ty] + i];
        s16x8 u = *(const s16x8*)(hbf + (size_t)s * DIM + l16 * 8);
#pragma unroll
        for (int q = 0; q < 8; ++q) ac[ty][q] += bf2f((unsigned short)u[q]);
      }
    }
  }
#pragma unroll
  for (int ty = 0; ty < 4; ++ty) {
    s16x8 o;
#pragma unroll
    for (int q = 0; q < 8; ++q) o[q] = (short)f2bf(ac[ty][q]);
    __builtin_nontemporal_store(
        o, (s16x8*)(agg4 + (size_t)ty * NNODES * DIM + (size_t)w * DIM + l16 * 8));
  }
}

// ---------------- K1 variant B: one node per 32-lane HALF-wave (R13 win) ---
__global__ __launch_bounds__(256) void agg4_half_kernel(const unsigned short* __restrict__ hbf,
                                                        const int* __restrict__ rp,
                                                        const int* __restrict__ esrc_s,
                                                        unsigned short* __restrict__ agg4) {
  int w = (blockIdx.x * 256 + threadIdx.x) >> 5;  // node = half-wave id
  int l32 = threadIdx.x & 31;                     // 4 cols per lane
  if (w >= NNODES) return;
  int beg[4], len[4];
#pragma unroll
  for (int ty = 0; ty < 4; ++ty) {
    beg[ty] = rp[ty * NNODES + w];
    len[ty] = rp[ty * NNODES + w + 1] - beg[ty];
  }
  int mx = max(max(len[0], len[1]), max(len[2], len[3]));
  float ac[4][4];
#pragma unroll
  for (int ty = 0; ty < 4; ++ty)
#pragma unroll
    for (int q = 0; q < 4; ++q) ac[ty][q] = 0.f;
#pragma unroll 2
  for (int i = 0; i < mx; ++i) {
#pragma unroll
    for (int ty = 0; ty < 4; ++ty) {
      if (i < len[ty]) {
        int s = esrc_s[beg[ty] + i];
        ushort4 u = *(const ushort4*)(hbf + (size_t)s * DIM + l32 * 4);
        ac[ty][0] += bf2f(u.x);
        ac[ty][1] += bf2f(u.y);
        ac[ty][2] += bf2f(u.z);
        ac[ty][3] += bf2f(u.w);
      }
    }
  }
#pragma unroll
  for (int ty = 0; ty < 4; ++ty) {
    unsigned long long packed =
        (unsigned long long)f2bf(ac[ty][0]) | ((unsigned long long)f2bf(ac[ty][1]) << 16) |
        ((unsigned long long)f2bf(ac[ty][2]) << 32) | ((unsigned long long)f2bf(ac[ty][3]) << 48);
    __builtin_nontemporal_store(
        packed,
        (unsigned long long*)(agg4 + (size_t)ty * NNODES * DIM + (size_t)w * DIM + l32 * 4));
  }
}

// ---------------- K2: abf = sum_ty agg4[ty] @ W_ty  (LDS-staged, pipelined)
__global__ __launch_bounds__(512, 2) void transform_kernel(const unsigned short* __restrict__ agg4,
                                                           const unsigned short* __restrict__ WeT,
                                                           unsigned short* __restrict__ abf) {
  __shared__ s16x8 lds[2][2048];
  const int t = threadIdx.x;
  const int wid = t >> 6, lane = t & 63;
  const int l15 = lane & 15, kg = lane >> 4;
  const int j0 = wid * 16, jb = j0 + kg * 4;

  s16x8 wf[4][4];
#pragma unroll
  for (int ty = 0; ty < 4; ++ty)
#pragma unroll
    for (int c = 0; c < 4; ++c)
      wf[ty][c] = *(const s16x8*)(WeT + (ty << 14) + ((j0 + l15) << 7) + c * 32 + kg * 8);

  int chk[4], lby[4];
#pragma unroll
  for (int i = 0; i < 4; ++i) {
    chk[i] = t + i * 512;
    int row = (chk[i] & 511) >> 4;
    int w16 = chk[i] & 15;
    lby[i] = (chk[i] >> 9) * 8192 + row * 256 + ((w16 ^ (row & 7)) << 4);
  }
  auto gsrc = [&](int i, int tile) -> const s16x8* {
    int ty = chk[i] >> 9;
    int row = (chk[i] & 511) >> 4;
    int w16 = chk[i] & 15;
    return (const s16x8*)(agg4 + (size_t)ty * NNODES * DIM +
                          (size_t)(tile * 32 + row) * DIM + w16 * 8);
  };

  int tile = blockIdx.x;
  if (tile >= NTILES) return;
  s16x8 st[4];
#pragma unroll
  for (int i = 0; i < 4; ++i) st[i] = __builtin_nontemporal_load(gsrc(i, tile));
#pragma unroll
  for (int i = 0; i < 4; ++i) *(s16x8*)((char*)&lds[0][0] + lby[i]) = st[i];
  int nx = tile + gridDim.x;
  bool hasnx = nx < NTILES;
  if (hasnx)
#pragma unroll
    for (int i = 0; i < 4; ++i) st[i] = __builtin_nontemporal_load(gsrc(i, nx));
  __syncthreads();
  int cur = 0;

  while (true) {
    if (hasnx) {
#pragma unroll
      for (int i = 0; i < 4; ++i) *(s16x8*)((char*)&lds[cur ^ 1][0] + lby[i]) = st[i];
    }
    int nx2 = nx + gridDim.x;
    bool has2 = hasnx && (nx2 < NTILES);
    if (has2) {
#pragma unroll
      for (int i = 0; i < 4; ++i) st[i] = __builtin_nontemporal_load(gsrc(i, nx2));
    }

    f32x4 acc[2] = {(f32x4){0.f, 0.f, 0.f, 0.f}, (f32x4){0.f, 0.f, 0.f, 0.f}};
    char* B0 = (char*)&lds[cur][0];
#pragma unroll
    for (int ty = 0; ty < 4; ++ty) {
#pragma unroll
      for (int c = 0; c < 4; ++c) {
        s16x8 afr[2];
#pragma unroll
        for (int nb = 0; nb < 2; ++nb) {
          int row = nb * 16 + l15;
          afr[nb] = *(const s16x8*)(B0 + ty * 8192 + row * 256 +
                                    ((c * 64 + kg * 16) ^ ((row & 7) << 4)));
        }
        acc[0] = MFMA(wf[ty][c], afr[0], acc[0]);
        acc[1] = MFMA(wf[ty][c], afr[1], acc[1]);
      }
    }
    const int n0 = tile * 32;
#pragma unroll
    for (int nb = 0; nb < 2; ++nb) {
      int n = n0 + nb * 16 + l15;
      ushort4 u = {f2bf(acc[nb][0]), f2bf(acc[nb][1]), f2bf(acc[nb][2]), f2bf(acc[nb][3])};
      *(ushort4*)(abf + (size_t)n * DIM + jb) = u;
    }
    __syncthreads();
    if (!hasnx) break;
    tile = nx;
    nx = nx2;
    hasnx = has2;
    cur ^= 1;
  }
}

// ---------------- K3: fused GRU via MFMA (LDS-staged, pipelined) -----------
__global__ __launch_bounds__(512, 2) void gru_mfma_kernel(const unsigned short* __restrict__ abf,
                                                          unsigned short* __restrict__ hbf,
                                                          const unsigned short* __restrict__ Wih,
                                                          const unsigned short* __restrict__ Whh,
                                                          const float* __restrict__ b_ih,
                                                          const float* __restrict__ b_hh) {
  __shared__ s16x8 lds[2][1024];
  const int t = threadIdx.x;
  const int wid = t >> 6, lane = t & 63;
  const int l15 = lane & 15, kg = lane >> 4;
  const int j0 = wid * 16, jb = j0 + kg * 4;

  s16x8 wI[3][4], wH[3][4];
#pragma unroll
  for (int g = 0; g < 3; ++g)
#pragma unroll
    for (int c = 0; c < 4; ++c) {
      int jrow = g * 128 + j0 + l15;
      wI[g][c] = *(const s16x8*)(Wih + (jrow << 7) + c * 32 + kg * 8);
      wH[g][c] = *(const s16x8*)(Whh + (jrow << 7) + c * 32 + kg * 8);
    }
  float4 bir = *(const float4*)(b_ih + jb);
  float4 biz = *(const float4*)(b_ih + 128 + jb);
  float4 bin_ = *(const float4*)(b_ih + 256 + jb);
  float4 bhr = *(const float4*)(b_hh + jb);
  float4 bhz = *(const float4*)(b_hh + 128 + jb);
  float4 bhn = *(const float4*)(b_hh + 256 + jb);

  int chk0 = t, chk1 = t + 512;
  int row0 = (chk0 & 511) >> 4, w160 = chk0 & 15;
  int row1 = (chk1 & 511) >> 4, w161 = chk1 & 15;
  int lb0 = (chk0 >> 9) * 8192 + row0 * 256 + ((w160 ^ (row0 & 7)) << 4);
  int lb1 = (chk1 >> 9) * 8192 + row1 * 256 + ((w161 ^ (row1 & 7)) << 4);
  int hbyte_lo = (jb * 2) & 15;
  int hbyte_slot = (jb * 2) >> 4;

  int tile = blockIdx.x;
  if (tile >= NTILES) return;
  s16x8 st0, st1;
  st0 = *(const s16x8*)(((chk0 >> 9) ? hbf : abf) + (size_t)(tile * 32 + row0) * DIM + w160 * 8);
  st1 = *(const s16x8*)(((chk1 >> 9) ? hbf : abf) + (size_t)(tile * 32 + row1) * DIM + w161 * 8);
  *(s16x8*)((char*)&lds[0][0] + lb0) = st0;
  *(s16x8*)((char*)&lds[0][0] + lb1) = st1;
  int nx = tile + gridDim.x;
  bool hasnx = nx < NTILES;
  if (hasnx) {
    st0 = *(const s16x8*)(((chk0 >> 9) ? hbf : abf) + (size_t)(nx * 32 + row0) * DIM + w160 * 8);
    st1 = *(const s16x8*)(((chk1 >> 9) ? hbf : abf) + (size_t)(nx * 32 + row1) * DIM + w161 * 8);
  }
  __syncthreads();
  int cur = 0;

  while (true) {
    if (hasnx) {
      *(s16x8*)((char*)&lds[cur ^ 1][0] + lb0) = st0;
      *(s16x8*)((char*)&lds[cur ^ 1][0] + lb1) = st1;
    }
    int nx2 = nx + gridDim.x;
    bool has2 = hasnx && (nx2 < NTILES);
    if (has2) {
      st0 = *(const s16x8*)(((chk0 >> 9) ? hbf : abf) + (size_t)(nx2 * 32 + row0) * DIM + w160 * 8);
      st1 = *(const s16x8*)(((chk1 >> 9) ? hbf : abf) + (size_t)(nx2 * 32 + row1) * DIM + w161 * 8);
    }

    f32x4 gi[3][2], gh[3][2];
#pragma unroll
    for (int g = 0; g < 3; ++g)
#pragma unroll
      for (int nb = 0; nb < 2; ++nb) {
        gi[g][nb] = (f32x4){0.f, 0.f, 0.f, 0.f};
        gh[g][nb] = (f32x4){0.f, 0.f, 0.f, 0.f};
      }
    char* aB = (char*)&lds[cur][0];
    char* hB = aB + 8192;
#pragma unroll
    for (int c = 0; c < 4; ++c) {
      s16x8 afr[2], hfr[2];
#pragma unroll
      for (int nb = 0; nb < 2; ++nb) {
        int row = nb * 16 + l15;
        int off = row * 256 + ((c * 64 + kg * 16) ^ ((row & 7) << 4));
        afr[nb] = *(const s16x8*)(aB + off);
        hfr[nb] = *(const s16x8*)(hB + off);
      }
#pragma unroll
      for (int g = 0; g < 3; ++g) {
        gi[g][0] = MFMA(wI[g][c], afr[0], gi[g][0]);
        gi[g][1] = MFMA(wI[g][c], afr[1], gi[g][1]);
        gh[g][0] = MFMA(wH[g][c], hfr[0], gh[g][0]);
        gh[g][1] = MFMA(wH[g][c], hfr[1], gh[g][1]);
      }
    }

    const int n0 = tile * 32;
#pragma unroll
    for (int nb = 0; nb < 2; ++nb) {
      int row = nb * 16 + l15;
      int n = n0 + row;
      int hb = row * 256 + ((hbyte_slot << 4) ^ ((row & 7) << 4)) + hbyte_lo;
      ushort4 hold4 = *(const ushort4*)(hB + hb);
      ushort4 outu;
#pragma unroll
      for (int reg = 0; reg < 4; ++reg) {
        float ir = gi[0][nb][reg] + ((const float*)&bir)[reg];
        float iz = gi[1][nb][reg] + ((const float*)&biz)[reg];
        float in_ = gi[2][nb][reg] + ((const float*)&bin_)[reg];
        float hr = gh[0][nb][reg] + ((const float*)&bhr)[reg];
        float hz = gh[1][nb][reg] + ((const float*)&bhz)[reg];
        float hn = gh[2][nb][reg] + ((const float*)&bhn)[reg];
        float r = 1.f / (1.f + __expf(-(ir + hr)));
        float z = 1.f / (1.f + __expf(-(iz + hz)));
        float x = in_ + r * hn;
        float ex = __expf(2.f * x);
        float nn = 1.f - 2.f / (ex + 1.f);  // tanh
        float ho = bf2f(((const unsigned short*)&hold4)[reg]);
        float hv = (1.f - z) * nn + z * ho;
        ((unsigned short*)&outu)[reg] = f2bf(hv);
      }
      *(ushort4*)(hbf + (size_t)n * DIM + jb) = outu;
    }
    __syncthreads();
    if (!hasnx) break;
    tile = nx;
    nx = nx2;
    hasnx = has2;
    cur ^= 1;
  }
}

// ---------------- pooled[g] = sum_{gid[n]==g} h[n] ----------------
__global__ __launch_bounds__(128) void pool_kernel(const unsigned short* __restrict__ h,
                                                   const int* __restrict__ gid,
                                                   float* __restrict__ pooled) {
  int j = threadIdx.x;
  int n0 = blockIdx.x * 32;
  int end = n0 + 32;
  if (end > NNODES) end = NNODES;
  int cur = gid[n0];
  float acc = 0.f;
  for (int n = n0; n < end; ++n) {
    int g = gid[n];
    if (g != cur) {
      atomicAdd(&pooled[cur * DIM + j], acc);
      acc = 0.f;
      cur = g;
    }
    acc += bf2f(h[(size_t)n * DIM + j]);
  }
  atomicAdd(&pooled[cur * DIM + j], acc);
}

// ---------------- logits + sigmoid ----------------
__global__ __launch_bounds__(128) void cls_kernel(const float* __restrict__ pooled,
                                                  const float* __restrict__ Wc,
                                                  const float* __restrict__ bc,
                                                  float* __restrict__ out) {
  int g = threadIdx.x;
  float acc = bc[0];
  for (int k = 0; k < DIM; ++k) acc = fmaf(pooled[g * DIM + k], Wc[k], acc);
  out[g] = 1.f / (1.f + __expf(-acc));
}

extern "C" void kernel_launch(void* const* d_in, const int* in_sizes, int n_in,
                              void* d_out, int out_size, void* d_ws, size_t ws_size,
                              hipStream_t stream) {
  const float* features = (const float*)d_in[0];
  const int* esrc = (const int*)d_in[1];
  const int* edst = (const int*)d_in[2];
  const int* etyp = (const int*)d_in[3];
  const int* gids = (const int*)d_in[4];
  const float* W_edge = (const float*)d_in[5];
  const float* W_ih = (const float*)d_in[6];
  const float* W_hh = (const float*)d_in[7];
  const float* b_ih = (const float*)d_in[8];
  const float* b_hh = (const float*)d_in[9];
  const float* W_cls = (const float*)d_in[10];
  const float* b_cls = (const float*)d_in[11];
  float* out = (float*)d_out;

  const size_t nd = (size_t)NNODES * DIM;
  char* p = (char*)d_ws;
  auto take = [&](size_t bytes) {
    char* q = p;
    p += (bytes + 15) & ~(size_t)15;
    return (void*)q;
  };
  unsigned short* agg4 = (unsigned short*)take(NETYPES * nd * 2);  // 102.4 MB
  unsigned short* abf = (unsigned short*)take(nd * 2);             // 25.6 MB
  unsigned short* hbf = (unsigned short*)take(nd * 2);             // 25.6 MB
  unsigned short* WeT = (unsigned short*)take(NETYPES * DIM * DIM * 2);
  unsigned short* Wihb = (unsigned short*)take(384 * DIM * 2);
  unsigned short* Whhb = (unsigned short*)take(384 * DIM * 2);
  int* rp = (int*)take((NBINS + 1) * 4);
  int* cursor = (int*)take(NBINS * 4);
  int* bsum = (int*)take(512 * 4);
  int* boffs = (int*)take(512 * 4);
  int* esrc_s = (int*)take(NEDGES * 4);
  float* pooled = (float*)take(NGRAPHS * DIM * 4);
  size_t need = (size_t)(p - (char*)d_ws);

  if (ws_size < need) {
    fill_kernel<<<(out_size + 127) / 128, 128, 0, stream>>>(out, out_size, 0.5f);
    return;
  }

  cvt_h_kernel<<<(int)(nd / 4 + 255) / 256, 256, 0, stream>>>(features, hbf, (int)(nd / 4));
  cvt_we_kernel<<<(NETYPES * DIM * DIM + 255) / 256, 256, 0, stream>>>(W_edge, WeT);
  cvt_w_kernel<<<(384 * DIM + 255) / 256, 256, 0, stream>>>(W_ih, Wihb, 384 * DIM);
  cvt_w_kernel<<<(384 * DIM + 255) / 256, 256, 0, stream>>>(W_hh, Whhb, 384 * DIM);

  hipMemsetAsync(cursor, 0, (size_t)NBINS * 4, stream);
  hist_kernel<<<(NEDGES + 255) / 256, 256, 0, stream>>>(edst, etyp, cursor);
  scan1_kernel<<<SCAN_BLK, 256, 0, stream>>>(cursor, rp, bsum);
  scan2_kernel<<<1, 512, 0, stream>>>(bsum, boffs, rp);
  scan3_kernel<<<SCAN_BLK, 256, 0, stream>>>(rp, boffs);
  hipMemcpyAsync(cursor, rp, (size_t)NBINS * 4, hipMemcpyDeviceToDevice, stream);
  fill_edges_kernel<<<(NEDGES + 255) / 256, 256, 0, stream>>>(esrc, edst, etyp, cursor, esrc_s);

  for (int s = 0; s < NSTEPS; ++s) {
    if ((s & 1) == 0)
      agg4_quart_kernel<<<(NNODES * 16 + 255) / 256, 256, 0, stream>>>(hbf, rp, esrc_s, agg4);
    else
      agg4_half_kernel<<<(NNODES * 32 + 255) / 256, 256, 0, stream>>>(hbf, rp, esrc_s, agg4);
    transform_kernel<<<PGRID, 512, 0, stream>>>(agg4, WeT, abf);
    gru_mfma_kernel<<<GRU_GRID, 512, 0, stream>>>(abf, hbf, Wihb, Whhb, b_ih, b_hh);
  }

  hipMemsetAsync(pooled, 0, (size_t)NGRAPHS * DIM * 4, stream);
  pool_kernel<<<(NNODES + 31) / 32, 128, 0, stream>>>(hbf, gids, pooled);
  cls_kernel<<<1, 128, 0, stream>>>(pooled, W_cls, b_cls, out);
}

// Round 15
// 1110.052 us; speedup vs baseline: 1.3769x; 1.0435x over previous
//
#include <hip/hip_runtime.h>
#include <cstdint>

#define NNODES 100000
#define NEDGES 600000
#define NETYPES 4
#define DIM 128
#define NSTEPS 8
#define NGRAPHS 128
#define NBINS (NETYPES * NNODES)
#define SCAN_BLK 391  // ceil(NBINS/1024)
#define NTILES (NNODES / 32)
#define PGRID 512
#define GRU_GRID 512

typedef short s16x8 __attribute__((ext_vector_type(8)));
typedef float f32x4 __attribute__((ext_vector_type(4)));

#define MFMA(a, b, c) __builtin_amdgcn_mfma_f32_16x16x32_bf16(a, b, c, 0, 0, 0)

static __device__ inline unsigned short f2bf(float x) {
  unsigned int u = __float_as_uint(x);
  unsigned int r = (u + 0x7FFFu + ((u >> 16) & 1u)) >> 16;
  return (unsigned short)r;
}
static __device__ inline float bf2f(unsigned short b) {
  return __uint_as_float(((unsigned int)b) << 16);
}

// ---------------- diagnostic fill ----------------
__global__ __launch_bounds__(128) void fill_kernel(float* __restrict__ out, int n, float v) {
  int i = blockIdx.x * 128 + threadIdx.x;
  if (i < n) out[i] = v;
}

// ---------------- fp32 -> bf16 converts ----------------
__global__ __launch_bounds__(256) void cvt_h_kernel(const float* __restrict__ f,
                                                    unsigned short* __restrict__ h, int n4) {
  int i = blockIdx.x * 256 + threadIdx.x;
  if (i < n4) {
    float4 v = ((const float4*)f)[i];
    ushort4 u = {f2bf(v.x), f2bf(v.y), f2bf(v.z), f2bf(v.w)};
    ((ushort4*)h)[i] = u;
  }
}

// W_edge [e][d][h] fp32 -> WeT [e][h][d] bf16 (j-major, k-contiguous)
__global__ __launch_bounds__(256) void cvt_we_kernel(const float* __restrict__ W,
                                                     unsigned short* __restrict__ WT) {
  int i = blockIdx.x * 256 + threadIdx.x;
  if (i < NETYPES * DIM * DIM) {
    int e = i >> 14;
    int r = i & 16383;
    int d = r >> 7;   // k
    int j = r & 127;  // output col
    WT[(e << 14) + (j << 7) + d] = f2bf(W[i]);
  }
}

__global__ __launch_bounds__(256) void cvt_w_kernel(const float* __restrict__ W,
                                                    unsigned short* __restrict__ Wb, int n) {
  int i = blockIdx.x * 256 + threadIdx.x;
  if (i < n) Wb[i] = f2bf(W[i]);
}

// ---------------- CSR build: histogram / scan / fill ----------------
__global__ __launch_bounds__(256) void hist_kernel(const int* __restrict__ edst,
                                                   const int* __restrict__ etyp,
                                                   int* __restrict__ bins) {
  int e = blockIdx.x * 256 + threadIdx.x;
  if (e < NEDGES) atomicAdd(&bins[etyp[e] * NNODES + edst[e]], 1);
}

__global__ __launch_bounds__(256) void scan1_kernel(const int* __restrict__ bins,
                                                    int* __restrict__ rp,
                                                    int* __restrict__ bsum) {
  __shared__ int sh[256];
  int b = blockIdx.x, t = threadIdx.x;
  int base = b * 1024 + t * 4;
  int v0 = 0, v1 = 0, v2 = 0, v3 = 0;
  if (base + 3 < NBINS) {
    int4 q = *(const int4*)(bins + base);
    v0 = q.x; v1 = q.y; v2 = q.z; v3 = q.w;
  } else {
    if (base < NBINS) v0 = bins[base];
    if (base + 1 < NBINS) v1 = bins[base + 1];
    if (base + 2 < NBINS) v2 = bins[base + 2];
  }
  int s = v0 + v1 + v2 + v3;
  sh[t] = s;
  __syncthreads();
  for (int off = 1; off < 256; off <<= 1) {
    int x = (t >= off) ? sh[t - off] : 0;
    __syncthreads();
    if (t >= off) sh[t] += x;
    __syncthreads();
  }
  int run = sh[t] - s;
  if (t == 255) bsum[b] = sh[255];
  if (base < NBINS) rp[base] = run;
  run += v0;
  if (base + 1 < NBINS) rp[base + 1] = run;
  run += v1;
  if (base + 2 < NBINS) rp[base + 2] = run;
  run += v2;
  if (base + 3 < NBINS) rp[base + 3] = run;
}

__global__ __launch_bounds__(512) void scan2_kernel(const int* __restrict__ bsum,
                                                    int* __restrict__ boffs,
                                                    int* __restrict__ rp) {
  __shared__ int sh[512];
  int t = threadIdx.x;
  int v = (t < SCAN_BLK) ? bsum[t] : 0;
  sh[t] = v;
  __syncthreads();
  for (int off = 1; off < 512; off <<= 1) {
    int x = (t >= off) ? sh[t - off] : 0;
    __syncthreads();
    if (t >= off) sh[t] += x;
    __syncthreads();
  }
  if (t < SCAN_BLK) boffs[t] = sh[t] - v;
  if (t == SCAN_BLK - 1) rp[NBINS] = sh[t];
}

__global__ __launch_bounds__(256) void scan3_kernel(int* __restrict__ rp,
                                                    const int* __restrict__ boffs) {
  int b = blockIdx.x, t = threadIdx.x;
  int base = b * 1024 + t * 4;
  int off = boffs[b];
#pragma unroll
  for (int i = 0; i < 4; ++i)
    if (base + i < NBINS) rp[base + i] += off;
}

__global__ __launch_bounds__(256) void fill_edges_kernel(const int* __restrict__ esrc,
                                                         const int* __restrict__ edst,
                                                         const int* __restrict__ etyp,
                                                         int* __restrict__ cursor,
                                                         int* __restrict__ esrc_s) {
  int e = blockIdx.x * 256 + threadIdx.x;
  if (e < NEDGES) {
    int slot = atomicAdd(&cursor[etyp[e] * NNODES + edst[e]], 1);
    esrc_s[slot] = esrc[e];
  }
}

// ---------------- K1: one node per 16-lane QUARTER-wave (R14 winner) -------
// s16x8/lane covers the 256B row with 16 lanes; 4 nodes share one instruction
// stream -> 16 independent gather streams in flight per wave.
__global__ __launch_bounds__(256) void agg4_quart_kernel(const unsigned short* __restrict__ hbf,
                                                         const int* __restrict__ rp,
                                                         const int* __restrict__ esrc_s,
                                                         unsigned short* __restrict__ agg4) {
  int w = (blockIdx.x * 256 + threadIdx.x) >> 4;  // node = quarter-wave id
  int l16 = threadIdx.x & 15;                     // 8 cols per lane
  if (w >= NNODES) return;
  int beg[4], len[4];
#pragma unroll
  for (int ty = 0; ty < 4; ++ty) {
    beg[ty] = rp[ty * NNODES + w];
    len[ty] = rp[ty * NNODES + w + 1] - beg[ty];
  }
  int mx = max(max(len[0], len[1]), max(len[2], len[3]));
  float ac[4][8];
#pragma unroll
  for (int ty = 0; ty < 4; ++ty)
#pragma unroll
    for (int q = 0; q < 8; ++q) ac[ty][q] = 0.f;
#pragma unroll 2
  for (int i = 0; i < mx; ++i) {
#pragma unroll
    for (int ty = 0; ty < 4; ++ty) {
      if (i < len[ty]) {
        int s = esrc_s[beg[ty] + i];
        s16x8 u = *(const s16x8*)(hbf + (size_t)s * DIM + l16 * 8);
#pragma unroll
        for (int q = 0; q < 8; ++q) ac[ty][q] += bf2f((unsigned short)u[q]);
      }
    }
  }
#pragma unroll
  for (int ty = 0; ty < 4; ++ty) {
    s16x8 o;
#pragma unroll
    for (int q = 0; q < 8; ++q) o[q] = (short)f2bf(ac[ty][q]);
    __builtin_nontemporal_store(
        o, (s16x8*)(agg4 + (size_t)ty * NNODES * DIM + (size_t)w * DIM + l16 * 8));
  }
}

// ---------------- K2: abf = sum_ty agg4[ty] @ W_ty  (LDS-staged, pipelined)
__global__ __launch_bounds__(512, 2) void transform_kernel(const unsigned short* __restrict__ agg4,
                                                           const unsigned short* __restrict__ WeT,
                                                           unsigned short* __restrict__ abf) {
  __shared__ s16x8 lds[2][2048];
  const int t = threadIdx.x;
  const int wid = t >> 6, lane = t & 63;
  const int l15 = lane & 15, kg = lane >> 4;
  const int j0 = wid * 16, jb = j0 + kg * 4;

  s16x8 wf[4][4];
#pragma unroll
  for (int ty = 0; ty < 4; ++ty)
#pragma unroll
    for (int c = 0; c < 4; ++c)
      wf[ty][c] = *(const s16x8*)(WeT + (ty << 14) + ((j0 + l15) << 7) + c * 32 + kg * 8);

  int chk[4], lby[4];
#pragma unroll
  for (int i = 0; i < 4; ++i) {
    chk[i] = t + i * 512;
    int row = (chk[i] & 511) >> 4;
    int w16 = chk[i] & 15;
    lby[i] = (chk[i] >> 9) * 8192 + row * 256 + ((w16 ^ (row & 7)) << 4);
  }
  auto gsrc = [&](int i, int tile) -> const s16x8* {
    int ty = chk[i] >> 9;
    int row = (chk[i] & 511) >> 4;
    int w16 = chk[i] & 15;
    return (const s16x8*)(agg4 + (size_t)ty * NNODES * DIM +
                          (size_t)(tile * 32 + row) * DIM + w16 * 8);
  };

  int tile = blockIdx.x;
  if (tile >= NTILES) return;
  s16x8 st[4];
#pragma unroll
  for (int i = 0; i < 4; ++i) st[i] = __builtin_nontemporal_load(gsrc(i, tile));
#pragma unroll
  for (int i = 0; i < 4; ++i) *(s16x8*)((char*)&lds[0][0] + lby[i]) = st[i];
  int nx = tile + gridDim.x;
  bool hasnx = nx < NTILES;
  if (hasnx)
#pragma unroll
    for (int i = 0; i < 4; ++i) st[i] = __builtin_nontemporal_load(gsrc(i, nx));
  __syncthreads();
  int cur = 0;

  while (true) {
    if (hasnx) {
#pragma unroll
      for (int i = 0; i < 4; ++i) *(s16x8*)((char*)&lds[cur ^ 1][0] + lby[i]) = st[i];
    }
    int nx2 = nx + gridDim.x;
    bool has2 = hasnx && (nx2 < NTILES);
    if (has2) {
#pragma unroll
      for (int i = 0; i < 4; ++i) st[i] = __builtin_nontemporal_load(gsrc(i, nx2));
    }

    f32x4 acc[2] = {(f32x4){0.f, 0.f, 0.f, 0.f}, (f32x4){0.f, 0.f, 0.f, 0.f}};
    char* B0 = (char*)&lds[cur][0];
#pragma unroll
    for (int ty = 0; ty < 4; ++ty) {
#pragma unroll
      for (int c = 0; c < 4; ++c) {
        s16x8 afr[2];
#pragma unroll
        for (int nb = 0; nb < 2; ++nb) {
          int row = nb * 16 + l15;
          afr[nb] = *(const s16x8*)(B0 + ty * 8192 + row * 256 +
                                    ((c * 64 + kg * 16) ^ ((row & 7) << 4)));
        }
        acc[0] = MFMA(wf[ty][c], afr[0], acc[0]);
        acc[1] = MFMA(wf[ty][c], afr[1], acc[1]);
      }
    }
    const int n0 = tile * 32;
#pragma unroll
    for (int nb = 0; nb < 2; ++nb) {
      int n = n0 + nb * 16 + l15;
      ushort4 u = {f2bf(acc[nb][0]), f2bf(acc[nb][1]), f2bf(acc[nb][2]), f2bf(acc[nb][3])};
      *(ushort4*)(abf + (size_t)n * DIM + jb) = u;
    }
    __syncthreads();
    if (!hasnx) break;
    tile = nx;
    nx = nx2;
    hasnx = has2;
    cur ^= 1;
  }
}

// ---------------- K3: fused GRU via MFMA (LDS-staged, pipelined) -----------
__global__ __launch_bounds__(512, 2) void gru_mfma_kernel(const unsigned short* __restrict__ abf,
                                                          unsigned short* __restrict__ hbf,
                                                          const unsigned short* __restrict__ Wih,
                                                          const unsigned short* __restrict__ Whh,
                                                          const float* __restrict__ b_ih,
                                                          const float* __restrict__ b_hh) {
  __shared__ s16x8 lds[2][1024];
  const int t = threadIdx.x;
  const int wid = t >> 6, lane = t & 63;
  const int l15 = lane & 15, kg = lane >> 4;
  const int j0 = wid * 16, jb = j0 + kg * 4;

  s16x8 wI[3][4], wH[3][4];
#pragma unroll
  for (int g = 0; g < 3; ++g)
#pragma unroll
    for (int c = 0; c < 4; ++c) {
      int jrow = g * 128 + j0 + l15;
      wI[g][c] = *(const s16x8*)(Wih + (jrow << 7) + c * 32 + kg * 8);
      wH[g][c] = *(const s16x8*)(Whh + (jrow << 7) + c * 32 + kg * 8);
    }
  float4 bir = *(const float4*)(b_ih + jb);
  float4 biz = *(const float4*)(b_ih + 128 + jb);
  float4 bin_ = *(const float4*)(b_ih + 256 + jb);
  float4 bhr = *(const float4*)(b_hh + jb);
  float4 bhz = *(const float4*)(b_hh + 128 + jb);
  float4 bhn = *(const float4*)(b_hh + 256 + jb);

  int chk0 = t, chk1 = t + 512;
  int row0 = (chk0 & 511) >> 4, w160 = chk0 & 15;
  int row1 = (chk1 & 511) >> 4, w161 = chk1 & 15;
  int lb0 = (chk0 >> 9) * 8192 + row0 * 256 + ((w160 ^ (row0 & 7)) << 4);
  int lb1 = (chk1 >> 9) * 8192 + row1 * 256 + ((w161 ^ (row1 & 7)) << 4);
  int hbyte_lo = (jb * 2) & 15;
  int hbyte_slot = (jb * 2) >> 4;

  int tile = blockIdx.x;
  if (tile >= NTILES) return;
  s16x8 st0, st1;
  st0 = *(const s16x8*)(((chk0 >> 9) ? hbf : abf) + (size_t)(tile * 32 + row0) * DIM + w160 * 8);
  st1 = *(const s16x8*)(((chk1 >> 9) ? hbf : abf) + (size_t)(tile * 32 + row1) * DIM + w161 * 8);
  *(s16x8*)((char*)&lds[0][0] + lb0) = st0;
  *(s16x8*)((char*)&lds[0][0] + lb1) = st1;
  int nx = tile + gridDim.x;
  bool hasnx = nx < NTILES;
  if (hasnx) {
    st0 = *(const s16x8*)(((chk0 >> 9) ? hbf : abf) + (size_t)(nx * 32 + row0) * DIM + w160 * 8);
    st1 = *(const s16x8*)(((chk1 >> 9) ? hbf : abf) + (size_t)(nx * 32 + row1) * DIM + w161 * 8);
  }
  __syncthreads();
  int cur = 0;

  while (true) {
    if (hasnx) {
      *(s16x8*)((char*)&lds[cur ^ 1][0] + lb0) = st0;
      *(s16x8*)((char*)&lds[cur ^ 1][0] + lb1) = st1;
    }
    int nx2 = nx + gridDim.x;
    bool has2 = hasnx && (nx2 < NTILES);
    if (has2) {
      st0 = *(const s16x8*)(((chk0 >> 9) ? hbf : abf) + (size_t)(nx2 * 32 + row0) * DIM + w160 * 8);
      st1 = *(const s16x8*)(((chk1 >> 9) ? hbf : abf) + (size_t)(nx2 * 32 + row1) * DIM + w161 * 8);
    }

    f32x4 gi[3][2], gh[3][2];
#pragma unroll
    for (int g = 0; g < 3; ++g)
#pragma unroll
      for (int nb = 0; nb < 2; ++nb) {
        gi[g][nb] = (f32x4){0.f, 0.f, 0.f, 0.f};
        gh[g][nb] = (f32x4){0.f, 0.f, 0.f, 0.f};
      }
    char* aB = (char*)&lds[cur][0];
    char* hB = aB + 8192;
#pragma unroll
    for (int c = 0; c < 4; ++c) {
      s16x8 afr[2], hfr[2];
#pragma unroll
      for (int nb = 0; nb < 2; ++nb) {
        int row = nb * 16 + l15;
        int off = row * 256 + ((c * 64 + kg * 16) ^ ((row & 7) << 4));
        afr[nb] = *(const s16x8*)(aB + off);
        hfr[nb] = *(const s16x8*)(hB + off);
      }
#pragma unroll
      for (int g = 0; g < 3; ++g) {
        gi[g][0] = MFMA(wI[g][c], afr[0], gi[g][0]);
        gi[g][1] = MFMA(wI[g][c], afr[1], gi[g][1]);
        gh[g][0] = MFMA(wH[g][c], hfr[0], gh[g][0]);
        gh[g][1] = MFMA(wH[g][c], hfr[1], gh[g][1]);
      }
    }

    const int n0 = tile * 32;
#pragma unroll
    for (int nb = 0; nb < 2; ++nb) {
      int row = nb * 16 + l15;
      int n = n0 + row;
      int hb = row * 256 + ((hbyte_slot << 4) ^ ((row & 7) << 4)) + hbyte_lo;
      ushort4 hold4 = *(const ushort4*)(hB + hb);
      ushort4 outu;
#pragma unroll
      for (int reg = 0; reg < 4; ++reg) {
        float ir = gi[0][nb][reg] + ((const float*)&bir)[reg];
        float iz = gi[1][nb][reg] + ((const float*)&biz)[reg];
        float in_ = gi[2][nb][reg] + ((const float*)&bin_)[reg];
        float hr = gh[0][nb][reg] + ((const float*)&bhr)[reg];
        float hz = gh[1][nb][reg] + ((const float*)&bhz)[reg];
        float hn = gh[2][nb][reg] + ((const float*)&bhn)[reg];
        float r = 1.f / (1.f + __expf(-(ir + hr)));
        float z = 1.f / (1.f + __expf(-(iz + hz)));
        float x = in_ + r * hn;
        float ex = __expf(2.f * x);
        float nn = 1.f - 2.f / (ex + 1.f);  // tanh
        float ho = bf2f(((const unsigned short*)&hold4)[reg]);
        float hv = (1.f - z) * nn + z * ho;
        ((unsigned short*)&outu)[reg] = f2bf(hv);
      }
      *(ushort4*)(hbf + (size_t)n * DIM + jb) = outu;
    }
    __syncthreads();
    if (!hasnx) break;
    tile = nx;
    nx = nx2;
    hasnx = has2;
    cur ^= 1;
  }
}

// ---------------- pooled[g] = sum_{gid[n]==g} h[n] ----------------
__global__ __launch_bounds__(128) void pool_kernel(const unsigned short* __restrict__ h,
                                                   const int* __restrict__ gid,
                                                   float* __restrict__ pooled) {
  int j = threadIdx.x;
  int n0 = blockIdx.x * 32;
  int end = n0 + 32;
  if (end > NNODES) end = NNODES;
  int cur = gid[n0];
  float acc = 0.f;
  for (int n = n0; n < end; ++n) {
    int g = gid[n];
    if (g != cur) {
      atomicAdd(&pooled[cur * DIM + j], acc);
      acc = 0.f;
      cur = g;
    }
    acc += bf2f(h[(size_t)n * DIM + j]);
  }
  atomicAdd(&pooled[cur * DIM + j], acc);
}

// ---------------- logits + sigmoid ----------------
__global__ __launch_bounds__(128) void cls_kernel(const float* __restrict__ pooled,
                                                  const float* __restrict__ Wc,
                                                  const float* __restrict__ bc,
                                                  float* __restrict__ out) {
  int g = threadIdx.x;
  float acc = bc[0];
  for (int k = 0; k < DIM; ++k) acc = fmaf(pooled[g * DIM + k], Wc[k], acc);
  out[g] = 1.f / (1.f + __expf(-acc));
}

extern "C" void kernel_launch(void* const* d_in, const int* in_sizes, int n_in,
                              void* d_out, int out_size, void* d_ws, size_t ws_size,
                              hipStream_t stream) {
  const float* features = (const float*)d_in[0];
  const int* esrc = (const int*)d_in[1];
  const int* edst = (const int*)d_in[2];
  const int* etyp = (const int*)d_in[3];
  const int* gids = (const int*)d_in[4];
  const float* W_edge = (const float*)d_in[5];
  const float* W_ih = (const float*)d_in[6];
  const float* W_hh = (const float*)d_in[7];
  const float* b_ih = (const float*)d_in[8];
  const float* b_hh = (const float*)d_in[9];
  const float* W_cls = (const float*)d_in[10];
  const float* b_cls = (const float*)d_in[11];
  float* out = (float*)d_out;

  const size_t nd = (size_t)NNODES * DIM;
  char* p = (char*)d_ws;
  auto take = [&](size_t bytes) {
    char* q = p;
    p += (bytes + 15) & ~(size_t)15;
    return (void*)q;
  };
  unsigned short* agg4 = (unsigned short*)take(NETYPES * nd * 2);  // 102.4 MB
  unsigned short* abf = (unsigned short*)take(nd * 2);             // 25.6 MB
  unsigned short* hbf = (unsigned short*)take(nd * 2);             // 25.6 MB
  unsigned short* WeT = (unsigned short*)take(NETYPES * DIM * DIM * 2);
  unsigned short* Wihb = (unsigned short*)take(384 * DIM * 2);
  unsigned short* Whhb = (unsigned short*)take(384 * DIM * 2);
  int* rp = (int*)take((NBINS + 1) * 4);
  int* cursor = (int*)take(NBINS * 4);
  int* bsum = (int*)take(512 * 4);
  int* boffs = (int*)take(512 * 4);
  int* esrc_s = (int*)take(NEDGES * 4);
  float* pooled = (float*)take(NGRAPHS * DIM * 4);
  size_t need = (size_t)(p - (char*)d_ws);

  if (ws_size < need) {
    fill_kernel<<<(out_size + 127) / 128, 128, 0, stream>>>(out, out_size, 0.5f);
    return;
  }

  cvt_h_kernel<<<(int)(nd / 4 + 255) / 256, 256, 0, stream>>>(features, hbf, (int)(nd / 4));
  cvt_we_kernel<<<(NETYPES * DIM * DIM + 255) / 256, 256, 0, stream>>>(W_edge, WeT);
  cvt_w_kernel<<<(384 * DIM + 255) / 256, 256, 0, stream>>>(W_ih, Wihb, 384 * DIM);
  cvt_w_kernel<<<(384 * DIM + 255) / 256, 256, 0, stream>>>(W_hh, Whhb, 384 * DIM);

  hipMemsetAsync(cursor, 0, (size_t)NBINS * 4, stream);
  hist_kernel<<<(NEDGES + 255) / 256, 256, 0, stream>>>(edst, etyp, cursor);
  scan1_kernel<<<SCAN_BLK, 256, 0, stream>>>(cursor, rp, bsum);
  scan2_kernel<<<1, 512, 0, stream>>>(bsum, boffs, rp);
  scan3_kernel<<<SCAN_BLK, 256, 0, stream>>>(rp, boffs);
  hipMemcpyAsync(cursor, rp, (size_t)NBINS * 4, hipMemcpyDeviceToDevice, stream);
  fill_edges_kernel<<<(NEDGES + 255) / 256, 256, 0, stream>>>(esrc, edst, etyp, cursor, esrc_s);

  for (int s = 0; s < NSTEPS; ++s) {
    agg4_quart_kernel<<<(NNODES * 16 + 255) / 256, 256, 0, stream>>>(hbf, rp, esrc_s, agg4);
    transform_kernel<<<PGRID, 512, 0, stream>>>(agg4, WeT, abf);
    gru_mfma_kernel<<<GRU_GRID, 512, 0, stream>>>(abf, hbf, Wihb, Whhb, b_ih, b_hh);
  }

  hipMemsetAsync(pooled, 0, (size_t)NGRAPHS * DIM * 4, stream);
  pool_kernel<<<(NNODES + 31) / 32, 128, 0, stream>>>(hbf, gids, pooled);
  cls_kernel<<<1, 128, 0, stream>>>(pooled, W_cls, b_cls, out);
}